// Round 7
// baseline (2071.226 us; speedup 1.0000x reference)
//
#include <hip/hip_runtime.h>
#include <math.h>

// Problem constants
#define BB 64
#define NN 100
#define HH 128
#define T3 384

// Output layout (floats, concatenated in return order)
#define O0 0            // sample_logprob [64,99]
#define O1 6336         // sample_distance [64,1]
#define O2 6400         // greedy_distance [64,1]
#define O3 6464         // predict_matrix [64,100,100,2]
#define O4 1286464      // greedy_solution_matrix [64,100,100]

#define TINYF 1.17549435e-38f
#define SCALEF 0.08838834764831845f

// padded register-friendly h layout: group k/16, 20-float stride (16B-aligned, bank-clean)
#define HIDX(k) ((((k) >> 4) * 20) + ((k) & 15))
#define HSTR 160   // 8 groups * 20

// ---------------- threefry2x32 (exact JAX implementation) ----------------
__device__ __forceinline__ unsigned rotl32(unsigned x, int d) {
    return (x << d) | (x >> (32 - d));
}

__device__ __forceinline__ void tf2x32(unsigned ks0, unsigned ks1,
                                       unsigned x0, unsigned x1,
                                       unsigned& o0, unsigned& o1) {
    unsigned ks2 = ks0 ^ ks1 ^ 0x1BD11BDAu;
    x0 += ks0; x1 += ks1;
    x0 += x1; x1 = rotl32(x1, 13); x1 ^= x0;
    x0 += x1; x1 = rotl32(x1, 15); x1 ^= x0;
    x0 += x1; x1 = rotl32(x1, 26); x1 ^= x0;
    x0 += x1; x1 = rotl32(x1, 6);  x1 ^= x0;
    x0 += ks1; x1 += ks2 + 1u;
    x0 += x1; x1 = rotl32(x1, 17); x1 ^= x0;
    x0 += x1; x1 = rotl32(x1, 29); x1 ^= x0;
    x0 += x1; x1 = rotl32(x1, 16); x1 ^= x0;
    x0 += x1; x1 = rotl32(x1, 24); x1 ^= x0;
    x0 += ks2; x1 += ks0 + 2u;
    x0 += x1; x1 = rotl32(x1, 13); x1 ^= x0;
    x0 += x1; x1 = rotl32(x1, 15); x1 ^= x0;
    x0 += x1; x1 = rotl32(x1, 26); x1 ^= x0;
    x0 += x1; x1 = rotl32(x1, 6);  x1 ^= x0;
    x0 += ks0; x1 += ks1 + 3u;
    x0 += x1; x1 = rotl32(x1, 17); x1 ^= x0;
    x0 += x1; x1 = rotl32(x1, 29); x1 ^= x0;
    x0 += x1; x1 = rotl32(x1, 16); x1 ^= x0;
    x0 += x1; x1 = rotl32(x1, 24); x1 ^= x0;
    x0 += ks1; x1 += ks2 + 4u;
    x0 += x1; x1 = rotl32(x1, 13); x1 ^= x0;
    x0 += x1; x1 = rotl32(x1, 15); x1 ^= x0;
    x0 += x1; x1 = rotl32(x1, 26); x1 ^= x0;
    x0 += x1; x1 = rotl32(x1, 6);  x1 ^= x0;
    x0 += ks2; x1 += ks0 + 5u;
    o0 = x0; o1 = x1;
}

__device__ __forceinline__ float gumbel_f(unsigned k0, unsigned k1, unsigned f) {
    unsigned o0, o1;
    tf2x32(k0, k1, 0u, f, o0, o1);
    unsigned bits = o0 ^ o1;
    float u01 = __uint_as_float((bits >> 9) | 0x3F800000u) - 1.0f;
    float u = fmaxf(TINYF, u01 * (1.0f - TINYF) + TINYF);
    return -logf(-logf(u));
}

// ---------------- encoder kernels ----------------

__global__ void k_embed(const float* __restrict__ node, const float* __restrict__ demand,
                        const float* __restrict__ Wn0, const float* __restrict__ bn0,
                        float* __restrict__ h) {
    int idx = blockIdx.x * 256 + threadIdx.x;
    if (idx >= BB * NN * HH) return;
    int r = idx >> 7, c = idx & 127;
    float v = node[r * 2] * Wn0[c] + node[r * 2 + 1] * Wn0[128 + c]
            + demand[r] * Wn0[256 + c] + bn0[c];
    h[idx] = fmaxf(v, 0.0f);
}

__global__ void k_adj(const float* __restrict__ dis, float* __restrict__ A) {
    int row = blockIdx.x;
    const float* d = dis + row * NN;
    int l = threadIdx.x;
    float v0 = (l < NN) ? -d[l] : -__builtin_inff();
    float v1 = (l + 64 < NN) ? -d[l + 64] : -__builtin_inff();
    float m = fmaxf(v0, v1);
    for (int off = 32; off > 0; off >>= 1) m = fmaxf(m, __shfl_xor(m, off));
    float e0 = (l < NN) ? expf(v0 - m) : 0.0f;
    float e1 = (l + 64 < NN) ? expf(v1 - m) : 0.0f;
    float s = e0 + e1;
    for (int off = 32; off > 0; off >>= 1) s += __shfl_xor(s, off);
    float inv = 1.0f / s;
    if (l < NN) A[row * NN + l] = e0 * inv;
    if (l + 64 < NN) A[row * NN + l + 64] = e1 * inv;
}

// out[6400x128] = h[6400x128] @ W[128x128]
__global__ void k_hw(const float* __restrict__ h, const float* __restrict__ W,
                     float* __restrict__ out) {
    __shared__ float hs[8 * 128];
    int block_row = blockIdx.x * 8;
    int tid = threadIdx.x;
    int col = tid & 127;
    int rg = tid >> 7;
    for (int i = tid; i < 8 * 128; i += 256) hs[i] = h[block_row * 128 + i];
    __syncthreads();
    float acc[4] = {0.f, 0.f, 0.f, 0.f};
    for (int k = 0; k < 128; k++) {
        float w = W[k * 128 + col];
#pragma unroll
        for (int r = 0; r < 4; r++) acc[r] += hs[(rg + 2 * r) * 128 + k] * w;
    }
#pragma unroll
    for (int r = 0; r < 4; r++)
        out[(block_row + rg + 2 * r) * 128 + col] = acc[r];
}

// out[6400x384] = h[6400x128] @ W[128x384] + bias[384]
__global__ void k_mm384(const float* __restrict__ h, const float* __restrict__ W,
                        const float* __restrict__ bias, float* __restrict__ out) {
    __shared__ float hs[8 * 128];
    int block_row = blockIdx.x * 8;
    int tid = threadIdx.x;
    int col = blockIdx.y * 128 + (tid & 127);
    int rg = tid >> 7;
    for (int i = tid; i < 8 * 128; i += 256) hs[i] = h[block_row * 128 + i];
    __syncthreads();
    float acc[4] = {0.f, 0.f, 0.f, 0.f};
    for (int k = 0; k < 128; k++) {
        float w = W[k * 384 + col];
#pragma unroll
        for (int r = 0; r < 4; r++) acc[r] += hs[(rg + 2 * r) * 128 + k] * w;
    }
    float b = bias[col];
#pragma unroll
    for (int r = 0; r < 4; r++)
        out[(block_row + rg + 2 * r) * 384 + col] = acc[r] + b;
}

__global__ void k_transpose128(const float* __restrict__ Wq, float* __restrict__ WqT) {
    int i = blockIdx.x * 256 + threadIdx.x;
    if (i >= 128 * 128) return;
    int k = i >> 7, c = i & 127;
    WqT[k * 128 + c] = Wq[c * 128 + k];
}

__global__ void k_agg(const float* __restrict__ h, const float* __restrict__ Ws,
                      const float* __restrict__ A, const float* __restrict__ hw,
                      float* __restrict__ out) {
    __shared__ float hs[4 * 128];
    __shared__ float As[4 * 100];
    int b = blockIdx.x / 25;
    int i0 = (blockIdx.x % 25) * 4;
    int tid = threadIdx.x;
    int col = tid & 127;
    int rg = tid >> 7;
    int rowbase = b * NN + i0;
    for (int idx = tid; idx < 4 * 128; idx += 256) hs[idx] = h[rowbase * 128 + idx];
    for (int idx = tid; idx < 4 * 100; idx += 256) As[idx] = A[rowbase * 100 + idx];
    __syncthreads();
    float acc0 = 0.f, acc1 = 0.f;
    for (int k = 0; k < 128; k++) {
        float w = Ws[k * 128 + col];
        acc0 += hs[rg * 128 + k] * w;
        acc1 += hs[(rg + 2) * 128 + k] * w;
    }
    const float* hwb = hw + b * NN * 128;
    for (int j = 0; j < NN; j++) {
        float v = hwb[j * 128 + col];
        acc0 += As[rg * 100 + j] * v;
        acc1 += As[(rg + 2) * 100 + j] * v;
    }
    out[(rowbase + rg) * 128 + col]     = fmaxf(acc0, 0.0f);
    out[(rowbase + rg + 2) * 128 + col] = fmaxf(acc1, 0.0f);
}

__global__ void k_predict(const float* __restrict__ dis, const float* __restrict__ We,
                          const float* __restrict__ be, const float* __restrict__ Wc,
                          const float* __restrict__ bc, float* __restrict__ out3) {
    __shared__ float sWe[128], sbe[128], sc0[128], sc1[128];
    int tid = threadIdx.x;
    if (tid < 128) {
        sWe[tid] = We[tid];
        sbe[tid] = be[tid];
        sc0[tid] = Wc[tid * 2];
        sc1[tid] = Wc[tid * 2 + 1];
    }
    __syncthreads();
    float b0 = bc[0], b1 = bc[1];
    for (int pos = blockIdx.x * 256 + tid; pos < BB * NN * NN; pos += gridDim.x * 256) {
        float d = dis[pos];
        float a0 = b0, a1 = b1;
        for (int k = 0; k < 128; k++) {
            float e = fmaxf(d * sWe[k] + sbe[k], 0.0f);
            a0 += e * sc0[k];
            a1 += e * sc1[k];
        }
        float m = fmaxf(a0, a1);
        float p0 = expf(a0 - m), p1 = expf(a1 - m);
        float inv = 1.0f / (p0 + p1);
        out3[pos * 2]     = p0 * inv;
        out3[pos * 2 + 1] = p1 * inv;
    }
}

__global__ void k_zero(float* __restrict__ p, int n) {
    int i = blockIdx.x * 256 + threadIdx.x;
    if (i < n) p[i] = 0.0f;
}

// ---------------- decoder v7: 4 CUs per batch, L2 exchange, 147 KB weights/CU/step ----
// grid 256 x 256 thr. Group g = batch, sub s in 0..3 owns gate cols
// {i,128+i,256+i : i in [32s,32s+32)}. Two device-scope barriers per step
// (h-quarter exchange + h1/logit-partial exchange), double-buffered by parity.
__global__ __launch_bounds__(256, 2) void k_decode7(
    const float* __restrict__ P0,       // [6400,384]
    const float* __restrict__ Z,        // [6400,128]
    const float* __restrict__ dis,
    const float* __restrict__ Wih,      // [2,128,384]
    const float* __restrict__ Whh,      // [2,128,384]
    const float* __restrict__ bih,
    const float* __restrict__ bhh,
    float* __restrict__ xch,            // [2][64][1536] exchange
    unsigned* __restrict__ flags,       // [64][32] counters
    float* __restrict__ out) {
    __shared__ float ZqT[32 * 100];         // 12.8 KB, [c][n]
    __shared__ float h0s[2 * HSTR], h1s[2 * HSTR];
    __shared__ float h0q[2 * 32], h1q[2 * 32];
    __shared__ float gi0[2 * 96];
    __shared__ float pgA[8 * 2 * 100];      // gh0 partials [ks][m][jloc]
    __shared__ float pgB[8 * 2 * 100];      // gh1
    __shared__ float pgC[8 * 2 * 100];      // gi1
    __shared__ float sb_hh0[96], sb_ih1[96], sb_hh1[96];
    __shared__ float logits[2 * 100];
    __shared__ float gum[100];
    __shared__ int s_ind2[2];

    const int tid = threadIdx.x;
    // XCD-aware swizzle: 4 subs of a group land on one XCD (heuristic, perf-only)
    const int nblk = blockIdx.x;
    const int xcd = nblk & 7, slot = nblk >> 3;
    const int g = xcd * 8 + (slot & 7);
    const int s = slot >> 3;
    const int b = g;

    const float* __restrict__ Whh0 = Whh;
    const float* __restrict__ Whh1 = Whh + 128 * T3;
    const float* __restrict__ Wih1 = Wih + 128 * T3;
    unsigned* flag = flags + g * 32;

    // matvec thread roles (tid < 192)
    const int jq = tid >> 3, ks = tid & 7;      // jq 0..23, ks 0..7
    const int run = jq >> 3, j4 = jq & 7;
    const int jabs = run * 128 + 32 * s + j4 * 4;
    const int jloc = run * 32 + j4 * 4;
    const int kb = ks * 16;

    // ---- static staging ----
    for (int i = tid; i < 3200; i += 256) {
        int c = i / 100, n = i - c * 100;
        ZqT[i] = Z[(b * NN + n) * 128 + 32 * s + c];
    }
    if (tid < 96) {
        int r = tid >> 5, il = tid & 31;
        int ja = r * 128 + 32 * s + il;
        sb_hh0[tid] = bhh[ja];
        sb_ih1[tid] = bih[T3 + ja];
        sb_hh1[tid] = bhh[T3 + ja];
    }
    if (tid < 256) {
        int m = tid >> 7, k = tid & 127;
        h0s[m * HSTR + HIDX(k)] = 0.0f;
        h1s[m * HSTR + HIDX(k)] = 0.0f;
    }
    if (tid == 0) { s_ind2[0] = 0; s_ind2[1] = 0; }

    unsigned kk0 = 0, kk1 = 0;
    tf2x32(0u, 42u, 0u, 0u, kk0, kk1);   // k1 of split(key(42)) — used by aux wave only

    int lastm = 0;
    float dist = 0.0f;
    __syncthreads();

    for (int t = 0; t < NN - 1; t++) {
        const int par = t & 1;
        float* xg  = xch + ((size_t)(par * 64 + g)) * 1536;
        float* xh0 = xg;            // [4][2][32]
        float* xh1 = xg + 256;      // [4][2][32]
        float* xlp = xg + 512;      // [4][2][100]

        // ===== phase A =====
        if (tid < 192) {
            // gh0 (Whh0 x h0_old) and gh1 (Whh1 x h1_old), both modes, 4 j, 16 k
            float4 hA[2][4], hB[2][4];
#pragma unroll
            for (int m = 0; m < 2; m++)
#pragma unroll
                for (int q = 0; q < 4; q++) {
                    hA[m][q] = *(const float4*)&h0s[m * HSTR + ks * 20 + 4 * q];
                    hB[m][q] = *(const float4*)&h1s[m * HSTR + ks * 20 + 4 * q];
                }
            float a0[2][4], a1[2][4];
#pragma unroll
            for (int m = 0; m < 2; m++)
#pragma unroll
                for (int j = 0; j < 4; j++) { a0[m][j] = 0.f; a1[m][j] = 0.f; }
#pragma unroll
            for (int q = 0; q < 4; q++) {
#pragma unroll
                for (int kk = 0; kk < 4; kk++) {
                    int k = kb + 4 * q + kk;
                    float4 w0 = *(const float4*)&Whh0[(size_t)k * T3 + jabs];
                    float4 w1 = *(const float4*)&Whh1[(size_t)k * T3 + jabs];
                    float hA0 = (kk == 0) ? hA[0][q].x : (kk == 1) ? hA[0][q].y : (kk == 2) ? hA[0][q].z : hA[0][q].w;
                    float hA1 = (kk == 0) ? hA[1][q].x : (kk == 1) ? hA[1][q].y : (kk == 2) ? hA[1][q].z : hA[1][q].w;
                    float hB0 = (kk == 0) ? hB[0][q].x : (kk == 1) ? hB[0][q].y : (kk == 2) ? hB[0][q].z : hB[0][q].w;
                    float hB1 = (kk == 0) ? hB[1][q].x : (kk == 1) ? hB[1][q].y : (kk == 2) ? hB[1][q].z : hB[1][q].w;
                    a0[0][0] += w0.x * hA0; a0[0][1] += w0.y * hA0; a0[0][2] += w0.z * hA0; a0[0][3] += w0.w * hA0;
                    a0[1][0] += w0.x * hA1; a0[1][1] += w0.y * hA1; a0[1][2] += w0.z * hA1; a0[1][3] += w0.w * hA1;
                    a1[0][0] += w1.x * hB0; a1[0][1] += w1.y * hB0; a1[0][2] += w1.z * hB0; a1[0][3] += w1.w * hB0;
                    a1[1][0] += w1.x * hB1; a1[1][1] += w1.y * hB1; a1[1][2] += w1.z * hB1; a1[1][3] += w1.w * hB1;
                }
            }
#pragma unroll
            for (int m = 0; m < 2; m++) {
                float4 o;
                o.x = a0[m][0]; o.y = a0[m][1]; o.z = a0[m][2]; o.w = a0[m][3];
                *(float4*)&pgA[(ks * 2 + m) * 100 + jloc] = o;
                o.x = a1[m][0]; o.y = a1[m][1]; o.z = a1[m][2]; o.w = a1[m][3];
                *(float4*)&pgB[(ks * 2 + m) * 100 + jloc] = o;
            }
        } else {
            // aux wave: RNG chain + gi0 row fetch + gumbel table
            int u = tid - 192;
            unsigned sk0, sk1, nkA, nkB;
            tf2x32(kk0, kk1, 0u, 1u, sk0, sk1);
            tf2x32(kk0, kk1, 0u, 0u, nkA, nkB);
            kk0 = nkA; kk1 = nkB;
            if (u < 48) {
                int m = u / 24, q = u - m * 24;
                int r = q >> 3, jj4 = q & 7;
                int ja = r * 128 + 32 * s + jj4 * 4;
                float4 g4 = *(const float4*)&P0[(size_t)(b * NN + s_ind2[m]) * T3 + ja];
                *(float4*)&gi0[m * 96 + r * 32 + jj4 * 4] = g4;
            }
            for (int u2 = u; u2 < NN; u2 += 64)
                gum[u2] = gumbel_f(sk0, sk1, (unsigned)(b * NN + u2));
        }
        __syncthreads();

        // ===== h0 update (own quarter) + publish =====
        if (tid < 64) {
            int m = tid >> 5, il = tid & 31;
            int i = 32 * s + il;
            float ghr = sb_hh0[il], ghz = sb_hh0[32 + il], ghn = sb_hh0[64 + il];
#pragma unroll
            for (int k8 = 0; k8 < 8; k8++) {
                int pb = (k8 * 2 + m) * 100;
                ghr += pgA[pb + il];
                ghz += pgA[pb + 32 + il];
                ghn += pgA[pb + 64 + il];
            }
            float rr = 1.0f / (1.0f + expf(-(gi0[m * 96 + il] + ghr)));
            float zz = 1.0f / (1.0f + expf(-(gi0[m * 96 + 32 + il] + ghz)));
            float nn = tanhf(gi0[m * 96 + 64 + il] + rr * ghn);
            float hnew = (1.0f - zz) * nn + zz * h0s[m * HSTR + HIDX(i)];
            h0q[m * 32 + il] = hnew;
            __hip_atomic_store(&xh0[(s * 2 + m) * 32 + il], hnew,
                               __ATOMIC_RELAXED, __HIP_MEMORY_SCOPE_AGENT);
        }
        __syncthreads();
        // ----- barrier 1 -----
        if (tid == 0) {
            __hip_atomic_fetch_add(flag, 1u, __ATOMIC_ACQ_REL, __HIP_MEMORY_SCOPE_AGENT);
            unsigned tgt = 8u * t + 4u;
            while (__hip_atomic_load(flag, __ATOMIC_ACQUIRE, __HIP_MEMORY_SCOPE_AGENT) < tgt)
                __builtin_amdgcn_s_sleep(2);
        }
        __syncthreads();
        // read full h0
        {
            int ss = tid >> 6, rem = tid & 63, m = rem >> 5, il = rem & 31;
            float v = __hip_atomic_load(&xh0[(ss * 2 + m) * 32 + il],
                                        __ATOMIC_RELAXED, __HIP_MEMORY_SCOPE_AGENT);
            int k = ss * 32 + il;
            h0s[m * HSTR + HIDX(k)] = v;
        }
        __syncthreads();

        // ===== phase B: gi1 = Wih1 quarter x full new h0 =====
        if (tid < 192) {
            float4 hA[2][4];
#pragma unroll
            for (int m = 0; m < 2; m++)
#pragma unroll
                for (int q = 0; q < 4; q++)
                    hA[m][q] = *(const float4*)&h0s[m * HSTR + ks * 20 + 4 * q];
            float a0[2][4];
#pragma unroll
            for (int m = 0; m < 2; m++)
#pragma unroll
                for (int j = 0; j < 4; j++) a0[m][j] = 0.f;
#pragma unroll
            for (int q = 0; q < 4; q++) {
#pragma unroll
                for (int kk = 0; kk < 4; kk++) {
                    int k = kb + 4 * q + kk;
                    float4 w = *(const float4*)&Wih1[(size_t)k * T3 + jabs];
                    float h0v = (kk == 0) ? hA[0][q].x : (kk == 1) ? hA[0][q].y : (kk == 2) ? hA[0][q].z : hA[0][q].w;
                    float h1v = (kk == 0) ? hA[1][q].x : (kk == 1) ? hA[1][q].y : (kk == 2) ? hA[1][q].z : hA[1][q].w;
                    a0[0][0] += w.x * h0v; a0[0][1] += w.y * h0v; a0[0][2] += w.z * h0v; a0[0][3] += w.w * h0v;
                    a0[1][0] += w.x * h1v; a0[1][1] += w.y * h1v; a0[1][2] += w.z * h1v; a0[1][3] += w.w * h1v;
                }
            }
#pragma unroll
            for (int m = 0; m < 2; m++) {
                float4 o;
                o.x = a0[m][0]; o.y = a0[m][1]; o.z = a0[m][2]; o.w = a0[m][3];
                *(float4*)&pgC[(ks * 2 + m) * 100 + jloc] = o;
            }
        }
        __syncthreads();

        // ===== h1 update (own quarter) + publish =====
        if (tid < 64) {
            int m = tid >> 5, il = tid & 31;
            int i = 32 * s + il;
            float gir = sb_ih1[il], giz = sb_ih1[32 + il], gin = sb_ih1[64 + il];
            float ghr = sb_hh1[il], ghz = sb_hh1[32 + il], ghn = sb_hh1[64 + il];
#pragma unroll
            for (int k8 = 0; k8 < 8; k8++) {
                int pb = (k8 * 2 + m) * 100;
                gir += pgC[pb + il];
                giz += pgC[pb + 32 + il];
                gin += pgC[pb + 64 + il];
                ghr += pgB[pb + il];
                ghz += pgB[pb + 32 + il];
                ghn += pgB[pb + 64 + il];
            }
            float rr = 1.0f / (1.0f + expf(-(gir + ghr)));
            float zz = 1.0f / (1.0f + expf(-(giz + ghz)));
            float nn = tanhf(gin + rr * ghn);
            float hnew = (1.0f - zz) * nn + zz * h1s[m * HSTR + HIDX(i)];
            h1q[m * 32 + il] = hnew;
            __hip_atomic_store(&xh1[(s * 2 + m) * 32 + il], hnew,
                               __ATOMIC_RELAXED, __HIP_MEMORY_SCOPE_AGENT);
        }
        __syncthreads();

        // ===== logit partials over own k-quarter (both modes) + publish =====
        if (tid < 200) {
            int mm = tid / 100, n = tid - mm * 100;
            float acc = 0.0f;
#pragma unroll 8
            for (int c = 0; c < 32; c++)
                acc += h1q[mm * 32 + c] * ZqT[c * 100 + n];
            __hip_atomic_store(&xlp[(s * 2 + mm) * 100 + n], acc,
                               __ATOMIC_RELAXED, __HIP_MEMORY_SCOPE_AGENT);
        }
        __syncthreads();
        // ----- barrier 2 -----
        if (tid == 0) {
            __hip_atomic_fetch_add(flag, 1u, __ATOMIC_ACQ_REL, __HIP_MEMORY_SCOPE_AGENT);
            unsigned tgt = 8u * t + 8u;
            while (__hip_atomic_load(flag, __ATOMIC_ACQUIRE, __HIP_MEMORY_SCOPE_AGENT) < tgt)
                __builtin_amdgcn_s_sleep(2);
        }
        __syncthreads();
        // read full h1 + summed logits
        {
            int ss = tid >> 6, rem = tid & 63, m = rem >> 5, il = rem & 31;
            float v = __hip_atomic_load(&xh1[(ss * 2 + m) * 32 + il],
                                        __ATOMIC_RELAXED, __HIP_MEMORY_SCOPE_AGENT);
            int k = ss * 32 + il;
            h1s[m * HSTR + HIDX(k)] = v;
        }
        if (tid < 200) {
            int mm = tid / 100, n = tid - mm * 100;
            float sum = 0.0f;
#pragma unroll
            for (int ss = 0; ss < 4; ss++)
                sum += __hip_atomic_load(&xlp[(ss * 2 + mm) * 100 + n],
                                         __ATOMIC_RELAXED, __HIP_MEMORY_SCOPE_AGENT);
            logits[mm * 100 + n] = sum * SCALEF;
        }
        __syncthreads();

        // ===== selection (wave0: sample, wave1: greedy) — identical in all subs =====
        if (tid < 128) {
            const int m = tid >> 6, lane = tid & 63;
            float v0 = logits[m * 100 + lane];
            float v1 = (lane + 64 < NN) ? logits[m * 100 + lane + 64] : -__builtin_inff();
            float mx = fmaxf(v0, v1);
            for (int off = 32; off > 0; off >>= 1) mx = fmaxf(mx, __shfl_xor(mx, off));
            float e = expf(v0 - mx) + ((lane + 64 < NN) ? expf(v1 - mx) : 0.0f);
            for (int off = 32; off > 0; off >>= 1) e += __shfl_xor(e, off);
            float a0 = v0, a1 = v1;
            if (m == 0) {
                a0 += gum[lane];
                if (lane + 64 < NN) a1 += gum[lane + 64];
            }
            float bv; int bi;
            if (a1 > a0) { bv = a1; bi = lane + 64; } else { bv = a0; bi = lane; }
            for (int off = 32; off > 0; off >>= 1) {
                float ov = __shfl_xor(bv, off);
                int   oi = __shfl_xor(bi, off);
                if (ov > bv || (ov == bv && oi < bi)) { bv = ov; bi = oi; }
            }
            int ind = bi;
            float la = __shfl(v0, ind & 63);
            float lb = __shfl(v1, ind & 63);
            float lv = (ind < 64) ? la : lb;
            if (lane == 0) {
                if (s == 0) {
                    if (m == 0) out[O0 + b * (NN - 1) + t] = lv - mx - logf(e);
                    else        out[O4 + (size_t)b * NN * NN + lastm * NN + ind] = 1.0f;
                }
                s_ind2[m] = ind;
            }
            dist += dis[b * NN * NN + lastm * NN + ind];
            lastm = ind;
        }
        __syncthreads();
    }

    if (s == 0 && tid == 0)  out[O1 + b] = dist;
    if (s == 0 && tid == 64) out[O2 + b] = dist;
}

// ---------------- fallback decoder v4 (round-4 verified, 771 us) ----------------
__device__ __forceinline__ void matvec_tile4(const float* __restrict__ W,
                                             const float* __restrict__ hp,
                                             int nk4,
                                             float* __restrict__ pg0,
                                             float* __restrict__ pg1) {
    float a00 = 0.f, a01 = 0.f, a02 = 0.f, a03 = 0.f;
    float a10 = 0.f, a11 = 0.f, a12 = 0.f, a13 = 0.f;
#pragma unroll 4
    for (int k4 = 0; k4 < nk4; ++k4) {
        float4 hA = *(const float4*)(hp + 4 * k4);
        float4 hB = *(const float4*)(hp + 132 + 4 * k4);
        const float* Wk = W + (size_t)(4 * k4) * T3;
        float4 w0 = *(const float4*)(Wk);
        float4 w1 = *(const float4*)(Wk + T3);
        float4 w2 = *(const float4*)(Wk + 2 * T3);
        float4 w3 = *(const float4*)(Wk + 3 * T3);
        a00 += hA.x * w0.x; a01 += hA.x * w0.y; a02 += hA.x * w0.z; a03 += hA.x * w0.w;
        a10 += hB.x * w0.x; a11 += hB.x * w0.y; a12 += hB.x * w0.z; a13 += hB.x * w0.w;
        a00 += hA.y * w1.x; a01 += hA.y * w1.y; a02 += hA.y * w1.z; a03 += hA.y * w1.w;
        a10 += hB.y * w1.x; a11 += hB.y * w1.y; a12 += hB.y * w1.z; a13 += hB.y * w1.w;
        a00 += hA.z * w2.x; a01 += hA.z * w2.y; a02 += hA.z * w2.z; a03 += hA.z * w2.w;
        a10 += hB.z * w2.x; a11 += hB.z * w2.y; a12 += hB.z * w2.z; a13 += hB.z * w2.w;
        a00 += hA.w * w3.x; a01 += hA.w * w3.y; a02 += hA.w * w3.z; a03 += hA.w * w3.w;
        a10 += hB.w * w3.x; a11 += hB.w * w3.y; a12 += hB.w * w3.z; a13 += hB.w * w3.w;
    }
    float4 o;
    o.x = a00; o.y = a01; o.z = a02; o.w = a03;
    *(float4*)pg0 = o;
    o.x = a10; o.y = a11; o.z = a12; o.w = a13;
    *(float4*)pg1 = o;
}

__global__ __launch_bounds__(512, 2) void k_decode4(
    const float* __restrict__ P0, const float* __restrict__ Z,
    const float* __restrict__ dis,
    const float* __restrict__ Wih, const float* __restrict__ Whh,
    const float* __restrict__ bih, const float* __restrict__ bhh,
    float* __restrict__ out) {
    __shared__ float Zs[NN * 132];
    __shared__ float h0s[2 * 132], h1s[2 * 132];
    __shared__ float gi0s[2 * 384];
    __shared__ float pgA[2 * 2 * 392];
    __shared__ float pgB[2 * 2 * 392];
    __shared__ float pgC[4 * 2 * 392];
    __shared__ float sbhh0[T3], sbih1[T3], sbhh1[T3];
    __shared__ float pl[2 * 2 * 100];
    __shared__ float gum[128];
    __shared__ int s_ind2[2];

    const int tid = threadIdx.x;
    const int b = blockIdx.x;
    const float* __restrict__ Wih1 = Wih + 128 * T3;

    for (int i4 = tid; i4 < NN * 32; i4 += 512) {
        int r = i4 >> 5, c4 = (i4 & 31) * 4;
        *(float4*)&Zs[r * 132 + c4] = *(const float4*)&Z[(b * NN + r) * 128 + c4];
    }
    if (tid < T3) {
        sbhh0[tid] = bhh[tid];
        sbih1[tid] = bih[T3 + tid];
        sbhh1[tid] = bhh[T3 + tid];
    }
    if (tid < 256) {
        int m = tid >> 7, i = tid & 127;
        h0s[m * 132 + i] = 0.0f;
        h1s[m * 132 + i] = 0.0f;
    }
    if (tid == 0) { s_ind2[0] = 0; s_ind2[1] = 0; }

    unsigned kk0, kk1;
    tf2x32(0u, 42u, 0u, 0u, kk0, kk1);

    int lastm = 0;
    float dist = 0.0f;
    __syncthreads();

    for (int t = 0; t < NN - 1; t++) {
        if (tid < 384) {
            const int unit = tid / 192;
            const int r = tid - unit * 192;
            const int ks = r / 96, j4 = r - ks * 96;
            const int j0 = j4 * 4, k0 = ks * 64;
            const float* W = Whh + unit * (128 * T3) + (size_t)k0 * T3 + j0;
            const float* hp = ((unit == 0) ? h0s : h1s) + k0;
            float* pg = (unit == 0) ? pgA : pgB;
            matvec_tile4(W, hp, 16,
                         &pg[(ks * 2 + 0) * 392 + j0],
                         &pg[(ks * 2 + 1) * 392 + j0]);
        } else {
            int u = tid - 384;
            int l0 = s_ind2[0], l1 = s_ind2[1];
#pragma unroll
            for (int q = 0; q < 6; q++) {
                int f = u + 128 * q;
                int m = (f >= 384) ? 1 : 0;
                int j = f - m * 384;
                gi0s[f] = P0[(size_t)(b * NN + (m ? l1 : l0)) * T3 + j];
            }
            unsigned sk0, sk1, nk0, nk1;
            tf2x32(kk0, kk1, 0u, 1u, sk0, sk1);
            tf2x32(kk0, kk1, 0u, 0u, nk0, nk1);
            kk0 = nk0; kk1 = nk1;
            if (u < NN) gum[u] = gumbel_f(sk0, sk1, (unsigned)(b * NN + u));
        }
        __syncthreads();

        if (tid < 256) {
            int m = tid >> 7, i = tid & 127;
            float ghr = pgA[(0 * 2 + m) * 392 + i]       + pgA[(1 * 2 + m) * 392 + i]       + sbhh0[i];
            float ghz = pgA[(0 * 2 + m) * 392 + i + 128] + pgA[(1 * 2 + m) * 392 + i + 128] + sbhh0[i + 128];
            float ghn = pgA[(0 * 2 + m) * 392 + i + 256] + pgA[(1 * 2 + m) * 392 + i + 256] + sbhh0[i + 256];
            float rr = 1.0f / (1.0f + expf(-(gi0s[m * 384 + i] + ghr)));
            float zz = 1.0f / (1.0f + expf(-(gi0s[m * 384 + i + 128] + ghz)));
            float nn = tanhf(gi0s[m * 384 + i + 256] + rr * ghn);
            h0s[m * 132 + i] = (1.0f - zz) * nn + zz * h0s[m * 132 + i];
        }
        __syncthreads();

        if (tid < 384) {
            const int ks = tid / 96, j4 = tid - ks * 96;
            const int j0 = j4 * 4, k0 = ks * 32;
            const float* W = Wih1 + (size_t)k0 * T3 + j0;
            matvec_tile4(W, h0s + k0, 8,
                         &pgC[(ks * 2 + 0) * 392 + j0],
                         &pgC[(ks * 2 + 1) * 392 + j0]);
        }
        __syncthreads();

        if (tid < 256) {
            int m = tid >> 7, i = tid & 127;
            float gir = sbih1[i], giz = sbih1[i + 128], gin = sbih1[i + 256];
#pragma unroll
            for (int ks = 0; ks < 4; ks++) {
                int pb = (ks * 2 + m) * 392;
                gir += pgC[pb + i];
                giz += pgC[pb + i + 128];
                gin += pgC[pb + i + 256];
            }
            float ghr = pgB[(0 * 2 + m) * 392 + i]       + pgB[(1 * 2 + m) * 392 + i]       + sbhh1[i];
            float ghz = pgB[(0 * 2 + m) * 392 + i + 128] + pgB[(1 * 2 + m) * 392 + i + 128] + sbhh1[i + 128];
            float ghn = pgB[(0 * 2 + m) * 392 + i + 256] + pgB[(1 * 2 + m) * 392 + i + 256] + sbhh1[i + 256];
            float rr = 1.0f / (1.0f + expf(-(gir + ghr)));
            float zz = 1.0f / (1.0f + expf(-(giz + ghz)));
            float nn = tanhf(gin + rr * ghn);
            h1s[m * 132 + i] = (1.0f - zz) * nn + zz * h1s[m * 132 + i];
        }
        __syncthreads();

        if (tid < 200) {
            int ks = tid / 100, n = tid - ks * 100;
            int kk0p = ks * 64;
            const float* Zp = &Zs[n * 132 + kk0p];
            const float* hp = &h1s[kk0p];
            float a0 = 0.f, a1 = 0.f;
#pragma unroll 4
            for (int q = 0; q < 16; q++) {
                float4 z4 = *(const float4*)(Zp + 4 * q);
                float4 hA = *(const float4*)(hp + 4 * q);
                float4 hB = *(const float4*)(hp + 132 + 4 * q);
                a0 += hA.x * z4.x; a0 += hA.y * z4.y; a0 += hA.z * z4.z; a0 += hA.w * z4.w;
                a1 += hB.x * z4.x; a1 += hB.y * z4.y; a1 += hB.z * z4.z; a1 += hB.w * z4.w;
            }
            pl[(0 * 2 + ks) * 100 + n] = a0;
            pl[(1 * 2 + ks) * 100 + n] = a1;
        }
        __syncthreads();

        if (tid < 128) {
            const int m = tid >> 6, lane = tid & 63;
            float v0, v1 = -__builtin_inff();
            v0 = (pl[(m * 2 + 0) * 100 + lane] + pl[(m * 2 + 1) * 100 + lane]) * SCALEF;
            if (lane + 64 < NN)
                v1 = (pl[(m * 2 + 0) * 100 + lane + 64] + pl[(m * 2 + 1) * 100 + lane + 64]) * SCALEF;
            float mx = fmaxf(v0, v1);
            for (int off = 32; off > 0; off >>= 1) mx = fmaxf(mx, __shfl_xor(mx, off));
            float e = expf(v0 - mx) + ((lane + 64 < NN) ? expf(v1 - mx) : 0.0f);
            for (int off = 32; off > 0; off >>= 1) e += __shfl_xor(e, off);
            float a0 = v0, a1 = v1;
            if (m == 0) {
                a0 += gum[lane];
                if (lane + 64 < NN) a1 += gum[lane + 64];
            }
            float bv; int bi;
            if (a1 > a0) { bv = a1; bi = lane + 64; } else { bv = a0; bi = lane; }
            for (int off = 32; off > 0; off >>= 1) {
                float ov = __shfl_xor(bv, off);
                int   oi = __shfl_xor(bi, off);
                if (ov > bv || (ov == bv && oi < bi)) { bv = ov; bi = oi; }
            }
            int ind = bi;
            float la = __shfl(v0, ind & 63);
            float lb = __shfl(v1, ind & 63);
            float lv = (ind < 64) ? la : lb;
            if (lane == 0) {
                if (m == 0) out[O0 + b * (NN - 1) + t] = lv - mx - logf(e);
                else        out[O4 + (size_t)b * NN * NN + lastm * NN + ind] = 1.0f;
                s_ind2[m] = ind;
            }
            dist += dis[b * NN * NN + lastm * NN + ind];
            lastm = ind;
        }
        __syncthreads();
    }

    if (tid == 0)  out[O1 + b] = dist;
    if (tid == 64) out[O2 + b] = dist;
}

// ---------------- host launcher ----------------
extern "C" void kernel_launch(void* const* d_in, const int* in_sizes, int n_in,
                              void* d_out, int out_size, void* d_ws, size_t ws_size,
                              hipStream_t stream) {
    (void)in_sizes; (void)n_in; (void)out_size;
    const float* node   = (const float*)d_in[0];
    const float* demand = (const float*)d_in[1];
    const float* dis    = (const float*)d_in[2];
    const float* Wn0    = (const float*)d_in[3];
    const float* bn0    = (const float*)d_in[4];
    const float* Ws     = (const float*)d_in[5];
    const float* Wngh   = (const float*)d_in[6];
    const float* We     = (const float*)d_in[7];
    const float* be     = (const float*)d_in[8];
    const float* Wih    = (const float*)d_in[9];
    const float* Whh    = (const float*)d_in[10];
    const float* bih    = (const float*)d_in[11];
    const float* bhh    = (const float*)d_in[12];
    const float* Wq     = (const float*)d_in[13];
    const float* Wc     = (const float*)d_in[14];
    const float* bc     = (const float*)d_in[15];
    float* out = (float*)d_out;
    float* ws  = (float*)d_ws;

    float* hA   = ws;                   // 819200
    float* hB   = ws + 819200;          // 819200
    float* hw   = ws + 1638400;         // Z after encoder
    float* A    = ws + 2457600;
    float* P0   = ws + 2457600;         // overlays A after encoder
    float* WqT  = ws + 4915200;         // 16384
    float* xch  = ws + 4931584;         // 2*64*1536 = 196608
    float* flagsF = ws + 5128192;       // 2048 u32
    const size_t need7 = (size_t)5130240 * 4;
    const size_t need4 = (size_t)4931584 * 4;

    hipLaunchKernelGGL(k_embed, dim3(3200), dim3(256), 0, stream, node, demand, Wn0, bn0, hA);
    hipLaunchKernelGGL(k_adj, dim3(6400), dim3(64), 0, stream, dis, A);

    float* cur = hA;
    float* nxt = hB;
    for (int l = 0; l < 3; l++) {
        hipLaunchKernelGGL(k_hw, dim3(800), dim3(256), 0, stream, cur, Wngh + l * 16384, hw);
        hipLaunchKernelGGL(k_agg, dim3(1600), dim3(256), 0, stream, cur, Ws + l * 16384, A, hw, nxt);
        float* tswap = cur; cur = nxt; nxt = tswap;
    }

    hipLaunchKernelGGL(k_predict, dim3(2500), dim3(256), 0, stream, dis, We, be, Wc, bc, out + O3);
    hipLaunchKernelGGL(k_zero, dim3(2500), dim3(256), 0, stream, out + O4, BB * NN * NN);

    hipLaunchKernelGGL(k_transpose128, dim3(64), dim3(256), 0, stream, Wq, WqT);
    hipLaunchKernelGGL(k_hw, dim3(800), dim3(256), 0, stream, cur, WqT, hw);   // Z
    hipLaunchKernelGGL(k_mm384, dim3(800, 3), dim3(256), 0, stream, cur, Wih, bih, P0);

    if (ws_size >= need7) {
        hipLaunchKernelGGL(k_zero, dim3(8), dim3(256), 0, stream, flagsF, 2048);
        hipLaunchKernelGGL(k_decode7, dim3(256), dim3(256), 0, stream,
                           P0, hw, dis, Wih, Whh, bih, bhh,
                           xch, (unsigned*)flagsF, out);
    } else {
        (void)need4;
        hipLaunchKernelGGL(k_decode4, dim3(64), dim3(512), 0, stream,
                           P0, hw, dis, Wih, Whh, bih, bhh, out);
    }
}

// Round 8
// 1149.745 us; speedup vs baseline: 1.8015x; 1.8015x over previous
//
#include <hip/hip_runtime.h>
#include <math.h>

// Problem constants
#define BB 64
#define NN 100
#define HH 128
#define T3 384

// Output layout (floats, concatenated in return order)
#define O0 0            // sample_logprob [64,99]
#define O1 6336         // sample_distance [64,1]
#define O2 6400         // greedy_distance [64,1]
#define O3 6464         // predict_matrix [64,100,100,2]
#define O4 1286464      // greedy_solution_matrix [64,100,100]

#define TINYF 1.17549435e-38f
#define SCALEF 0.08838834764831845f

// ---------------- threefry2x32 (exact JAX implementation) ----------------
__device__ __forceinline__ unsigned rotl32(unsigned x, int d) {
    return (x << d) | (x >> (32 - d));
}

__device__ __forceinline__ void tf2x32(unsigned ks0, unsigned ks1,
                                       unsigned x0, unsigned x1,
                                       unsigned& o0, unsigned& o1) {
    unsigned ks2 = ks0 ^ ks1 ^ 0x1BD11BDAu;
    x0 += ks0; x1 += ks1;
    x0 += x1; x1 = rotl32(x1, 13); x1 ^= x0;
    x0 += x1; x1 = rotl32(x1, 15); x1 ^= x0;
    x0 += x1; x1 = rotl32(x1, 26); x1 ^= x0;
    x0 += x1; x1 = rotl32(x1, 6);  x1 ^= x0;
    x0 += ks1; x1 += ks2 + 1u;
    x0 += x1; x1 = rotl32(x1, 17); x1 ^= x0;
    x0 += x1; x1 = rotl32(x1, 29); x1 ^= x0;
    x0 += x1; x1 = rotl32(x1, 16); x1 ^= x0;
    x0 += x1; x1 = rotl32(x1, 24); x1 ^= x0;
    x0 += ks2; x1 += ks0 + 2u;
    x0 += x1; x1 = rotl32(x1, 13); x1 ^= x0;
    x0 += x1; x1 = rotl32(x1, 15); x1 ^= x0;
    x0 += x1; x1 = rotl32(x1, 26); x1 ^= x0;
    x0 += x1; x1 = rotl32(x1, 6);  x1 ^= x0;
    x0 += ks0; x1 += ks1 + 3u;
    x0 += x1; x1 = rotl32(x1, 17); x1 ^= x0;
    x0 += x1; x1 = rotl32(x1, 29); x1 ^= x0;
    x0 += x1; x1 = rotl32(x1, 16); x1 ^= x0;
    x0 += x1; x1 = rotl32(x1, 24); x1 ^= x0;
    x0 += ks1; x1 += ks2 + 4u;
    x0 += x1; x1 = rotl32(x1, 13); x1 ^= x0;
    x0 += x1; x1 = rotl32(x1, 15); x1 ^= x0;
    x0 += x1; x1 = rotl32(x1, 26); x1 ^= x0;
    x0 += x1; x1 = rotl32(x1, 6);  x1 ^= x0;
    x0 += ks2; x1 += ks0 + 5u;
    o0 = x0; o1 = x1;
}

__device__ __forceinline__ float gumbel_f(unsigned k0, unsigned k1, unsigned f) {
    unsigned o0, o1;
    tf2x32(k0, k1, 0u, f, o0, o1);
    unsigned bits = o0 ^ o1;
    float u01 = __uint_as_float((bits >> 9) | 0x3F800000u) - 1.0f;
    float u = fmaxf(TINYF, u01 * (1.0f - TINYF) + TINYF);
    return -logf(-logf(u));
}

// ---------------- encoder kernels ----------------

__global__ void k_embed(const float* __restrict__ node, const float* __restrict__ demand,
                        const float* __restrict__ Wn0, const float* __restrict__ bn0,
                        float* __restrict__ h) {
    int idx = blockIdx.x * 256 + threadIdx.x;
    if (idx >= BB * NN * HH) return;
    int r = idx >> 7, c = idx & 127;
    float v = node[r * 2] * Wn0[c] + node[r * 2 + 1] * Wn0[128 + c]
            + demand[r] * Wn0[256 + c] + bn0[c];
    h[idx] = fmaxf(v, 0.0f);
}

__global__ void k_adj(const float* __restrict__ dis, float* __restrict__ A) {
    int row = blockIdx.x;
    const float* d = dis + row * NN;
    int l = threadIdx.x;
    float v0 = (l < NN) ? -d[l] : -__builtin_inff();
    float v1 = (l + 64 < NN) ? -d[l + 64] : -__builtin_inff();
    float m = fmaxf(v0, v1);
    for (int off = 32; off > 0; off >>= 1) m = fmaxf(m, __shfl_xor(m, off));
    float e0 = (l < NN) ? expf(v0 - m) : 0.0f;
    float e1 = (l + 64 < NN) ? expf(v1 - m) : 0.0f;
    float s = e0 + e1;
    for (int off = 32; off > 0; off >>= 1) s += __shfl_xor(s, off);
    float inv = 1.0f / s;
    if (l < NN) A[row * NN + l] = e0 * inv;
    if (l + 64 < NN) A[row * NN + l + 64] = e1 * inv;
}

// out[6400x128] = h[6400x128] @ W[128x128]
__global__ void k_hw(const float* __restrict__ h, const float* __restrict__ W,
                     float* __restrict__ out) {
    __shared__ float hs[8 * 128];
    int block_row = blockIdx.x * 8;
    int tid = threadIdx.x;
    int col = tid & 127;
    int rg = tid >> 7;
    for (int i = tid; i < 8 * 128; i += 256) hs[i] = h[block_row * 128 + i];
    __syncthreads();
    float acc[4] = {0.f, 0.f, 0.f, 0.f};
    for (int k = 0; k < 128; k++) {
        float w = W[k * 128 + col];
#pragma unroll
        for (int r = 0; r < 4; r++) acc[r] += hs[(rg + 2 * r) * 128 + k] * w;
    }
#pragma unroll
    for (int r = 0; r < 4; r++)
        out[(block_row + rg + 2 * r) * 128 + col] = acc[r];
}

// out[6400x384] = h[6400x128] @ W[128x384] + bias[384]
__global__ void k_mm384(const float* __restrict__ h, const float* __restrict__ W,
                        const float* __restrict__ bias, float* __restrict__ out) {
    __shared__ float hs[8 * 128];
    int block_row = blockIdx.x * 8;
    int tid = threadIdx.x;
    int col = blockIdx.y * 128 + (tid & 127);
    int rg = tid >> 7;
    for (int i = tid; i < 8 * 128; i += 256) hs[i] = h[block_row * 128 + i];
    __syncthreads();
    float acc[4] = {0.f, 0.f, 0.f, 0.f};
    for (int k = 0; k < 128; k++) {
        float w = W[k * 384 + col];
#pragma unroll
        for (int r = 0; r < 4; r++) acc[r] += hs[(rg + 2 * r) * 128 + k] * w;
    }
    float b = bias[col];
#pragma unroll
    for (int r = 0; r < 4; r++)
        out[(block_row + rg + 2 * r) * 384 + col] = acc[r] + b;
}

__global__ void k_transpose128(const float* __restrict__ Wq, float* __restrict__ WqT) {
    int i = blockIdx.x * 256 + threadIdx.x;
    if (i >= 128 * 128) return;
    int k = i >> 7, c = i & 127;
    WqT[k * 128 + c] = Wq[c * 128 + k];
}

__global__ void k_agg(const float* __restrict__ h, const float* __restrict__ Ws,
                      const float* __restrict__ A, const float* __restrict__ hw,
                      float* __restrict__ out) {
    __shared__ float hs[4 * 128];
    __shared__ float As[4 * 100];
    int b = blockIdx.x / 25;
    int i0 = (blockIdx.x % 25) * 4;
    int tid = threadIdx.x;
    int col = tid & 127;
    int rg = tid >> 7;
    int rowbase = b * NN + i0;
    for (int idx = tid; idx < 4 * 128; idx += 256) hs[idx] = h[rowbase * 128 + idx];
    for (int idx = tid; idx < 4 * 100; idx += 256) As[idx] = A[rowbase * 100 + idx];
    __syncthreads();
    float acc0 = 0.f, acc1 = 0.f;
    for (int k = 0; k < 128; k++) {
        float w = Ws[k * 128 + col];
        acc0 += hs[rg * 128 + k] * w;
        acc1 += hs[(rg + 2) * 128 + k] * w;
    }
    const float* hwb = hw + b * NN * 128;
    for (int j = 0; j < NN; j++) {
        float v = hwb[j * 128 + col];
        acc0 += As[rg * 100 + j] * v;
        acc1 += As[(rg + 2) * 100 + j] * v;
    }
    out[(rowbase + rg) * 128 + col]     = fmaxf(acc0, 0.0f);
    out[(rowbase + rg + 2) * 128 + col] = fmaxf(acc1, 0.0f);
}

__global__ void k_predict(const float* __restrict__ dis, const float* __restrict__ We,
                          const float* __restrict__ be, const float* __restrict__ Wc,
                          const float* __restrict__ bc, float* __restrict__ out3) {
    __shared__ float sWe[128], sbe[128], sc0[128], sc1[128];
    int tid = threadIdx.x;
    if (tid < 128) {
        sWe[tid] = We[tid];
        sbe[tid] = be[tid];
        sc0[tid] = Wc[tid * 2];
        sc1[tid] = Wc[tid * 2 + 1];
    }
    __syncthreads();
    float b0 = bc[0], b1 = bc[1];
    for (int pos = blockIdx.x * 256 + tid; pos < BB * NN * NN; pos += gridDim.x * 256) {
        float d = dis[pos];
        float a0 = b0, a1 = b1;
        for (int k = 0; k < 128; k++) {
            float e = fmaxf(d * sWe[k] + sbe[k], 0.0f);
            a0 += e * sc0[k];
            a1 += e * sc1[k];
        }
        float m = fmaxf(a0, a1);
        float p0 = expf(a0 - m), p1 = expf(a1 - m);
        float inv = 1.0f / (p0 + p1);
        out3[pos * 2]     = p0 * inv;
        out3[pos * 2 + 1] = p1 * inv;
    }
}

__global__ void k_zero(float* __restrict__ p, int n) {
    int i = blockIdx.x * 256 + threadIdx.x;
    if (i < n) p[i] = 0.0f;
}

// ---------------- shared matvec tile (spill-proof, ~40 VGPR) ----------------
__device__ __forceinline__ void matvec_tile4(const float* __restrict__ W,   // &W[k0*384 + j0]
                                             const float* __restrict__ hp,  // &h[k0]; modes +0,+132
                                             int nk4,
                                             float* __restrict__ pg0,
                                             float* __restrict__ pg1) {
    float a00 = 0.f, a01 = 0.f, a02 = 0.f, a03 = 0.f;
    float a10 = 0.f, a11 = 0.f, a12 = 0.f, a13 = 0.f;
#pragma unroll 4
    for (int k4 = 0; k4 < nk4; ++k4) {
        float4 hA = *(const float4*)(hp + 4 * k4);
        float4 hB = *(const float4*)(hp + 132 + 4 * k4);
        const float* Wk = W + (size_t)(4 * k4) * T3;
        float4 w0 = *(const float4*)(Wk);
        float4 w1 = *(const float4*)(Wk + T3);
        float4 w2 = *(const float4*)(Wk + 2 * T3);
        float4 w3 = *(const float4*)(Wk + 3 * T3);
        a00 += hA.x * w0.x; a01 += hA.x * w0.y; a02 += hA.x * w0.z; a03 += hA.x * w0.w;
        a10 += hB.x * w0.x; a11 += hB.x * w0.y; a12 += hB.x * w0.z; a13 += hB.x * w0.w;
        a00 += hA.y * w1.x; a01 += hA.y * w1.y; a02 += hA.y * w1.z; a03 += hA.y * w1.w;
        a10 += hB.y * w1.x; a11 += hB.y * w1.y; a12 += hB.y * w1.z; a13 += hB.y * w1.w;
        a00 += hA.z * w2.x; a01 += hA.z * w2.y; a02 += hA.z * w2.z; a03 += hA.z * w2.w;
        a10 += hB.z * w2.x; a11 += hB.z * w2.y; a12 += hB.z * w2.z; a13 += hB.z * w2.w;
        a00 += hA.w * w3.x; a01 += hA.w * w3.y; a02 += hA.w * w3.z; a03 += hA.w * w3.w;
        a10 += hB.w * w3.x; a11 += hB.w * w3.y; a12 += hB.w * w3.z; a13 += hB.w * w3.w;
    }
    float4 o;
    o.x = a00; o.y = a01; o.z = a02; o.w = a03;
    *(float4*)pg0 = o;
    o.x = a10; o.y = a11; o.z = a12; o.w = a13;
    *(float4*)pg1 = o;
}

// ---------------- decoder v8: decode4 structure, 1024 threads (16 waves/CU) ----------
// Phase A: 768 threads stream Whh0+Whh1 (12 waves of loads in flight vs decode4's 6).
// Phase C: 768 threads stream Wih1. 256 aux threads: gi0 prefetch + RNG + gumbel.
__global__ __launch_bounds__(1024, 1) void k_decode8(
    const float* __restrict__ P0,       // [6400, 384]  x@Wih0 + bih0
    const float* __restrict__ Z,        // [6400, 128]  x@Wq^T
    const float* __restrict__ dis,
    const float* __restrict__ Wih,      // [2,128,384]
    const float* __restrict__ Whh,      // [2,128,384]
    const float* __restrict__ bih,
    const float* __restrict__ bhh,
    float* __restrict__ out) {
    __shared__ float Zs[NN * 132];          // 52.8 KB
    __shared__ float h0s[2 * 132], h1s[2 * 132];
    __shared__ float gi0s[2 * 384];
    __shared__ float pgA[4 * 2 * 392];      // gh0 partials [ks4][m][392]
    __shared__ float pgB[4 * 2 * 392];      // gh1 partials
    __shared__ float pgC[8 * 2 * 392];      // gi1 partials [ks8][m][392]
    __shared__ float sbhh0[T3], sbih1[T3], sbhh1[T3];
    __shared__ float pl[2 * 2 * 100];       // [m][ks][n]
    __shared__ float gum[128];
    __shared__ int s_ind2[2];

    const int tid = threadIdx.x;
    const int b = blockIdx.x;

    const float* __restrict__ Wih1 = Wih + 128 * T3;

    // ---- static staging ----
    for (int i4 = tid; i4 < NN * 32; i4 += 1024) {
        int r = i4 >> 5, c4 = (i4 & 31) * 4;
        *(float4*)&Zs[r * 132 + c4] = *(const float4*)&Z[(b * NN + r) * 128 + c4];
    }
    if (tid < T3) {
        sbhh0[tid] = bhh[tid];
        sbih1[tid] = bih[T3 + tid];
        sbhh1[tid] = bhh[T3 + tid];
    }
    if (tid < 256) {
        int m = tid >> 7, i = tid & 127;
        h0s[m * 132 + i] = 0.0f;
        h1s[m * 132 + i] = 0.0f;
    }
    if (tid == 0) { s_ind2[0] = 0; s_ind2[1] = 0; }

    unsigned kk0, kk1;
    tf2x32(0u, 42u, 0u, 0u, kk0, kk1);   // k1 of split(key(42)) — advanced by aux threads

    int lastm = 0;       // tracked by tid<128 (selection threads)
    float dist = 0.0f;
    __syncthreads();

    for (int t = 0; t < NN - 1; t++) {
        // ===== phase A: gh0 & gh1 partials (768 thr); aux 256 thr: gi0 + RNG + gumbel =====
        if (tid < 768) {
            const int unit = tid / 384;              // 0: Whh0*h0, 1: Whh1*h1
            const int r = tid - unit * 384;
            const int ks = r / 96, j4 = r - ks * 96; // ks 0..3 (32 k), j4 0..95
            const int j0 = j4 * 4, k0 = ks * 32;
            const float* W = Whh + unit * (128 * T3) + (size_t)k0 * T3 + j0;
            const float* hp = ((unit == 0) ? h0s : h1s) + k0;
            float* pg = (unit == 0) ? pgA : pgB;
            matvec_tile4(W, hp, 8,
                         &pg[(ks * 2 + 0) * 392 + j0],
                         &pg[(ks * 2 + 1) * 392 + j0]);
        } else {
            int u = tid - 768;                       // 0..255
            int l0 = s_ind2[0], l1 = s_ind2[1];
#pragma unroll
            for (int q = 0; q < 3; q++) {
                int f = u + 256 * q;
                int m = (f >= 384) ? 1 : 0;
                int j = f - m * 384;
                gi0s[f] = P0[(size_t)(b * NN + (m ? l1 : l0)) * T3 + j];
            }
            unsigned sk0, sk1, nk0, nk1;
            tf2x32(kk0, kk1, 0u, 1u, sk0, sk1);
            tf2x32(kk0, kk1, 0u, 0u, nk0, nk1);
            kk0 = nk0; kk1 = nk1;
            if (u < NN) gum[u] = gumbel_f(sk0, sk1, (unsigned)(b * NN + u));
        }
        __syncthreads();

        // ===== phase B: h0 update (256 thr) =====
        if (tid < 256) {
            int m = tid >> 7, i = tid & 127;
            float ghr = sbhh0[i], ghz = sbhh0[i + 128], ghn = sbhh0[i + 256];
#pragma unroll
            for (int ks = 0; ks < 4; ks++) {
                int pb = (ks * 2 + m) * 392;
                ghr += pgA[pb + i];
                ghz += pgA[pb + i + 128];
                ghn += pgA[pb + i + 256];
            }
            float rr = 1.0f / (1.0f + expf(-(gi0s[m * 384 + i] + ghr)));
            float zz = 1.0f / (1.0f + expf(-(gi0s[m * 384 + i + 128] + ghz)));
            float nn = tanhf(gi0s[m * 384 + i + 256] + rr * ghn);
            h0s[m * 132 + i] = (1.0f - zz) * nn + zz * h0s[m * 132 + i];
        }
        __syncthreads();

        // ===== phase C: gi1 partials (768 thr, 8 k-slices of 16) =====
        if (tid < 768) {
            const int ks = tid / 96, j4 = tid - ks * 96;   // ks 0..7
            const int j0 = j4 * 4, k0 = ks * 16;
            const float* W = Wih1 + (size_t)k0 * T3 + j0;
            matvec_tile4(W, h0s + k0, 4,
                         &pgC[(ks * 2 + 0) * 392 + j0],
                         &pgC[(ks * 2 + 1) * 392 + j0]);
        }
        __syncthreads();

        // ===== phase D: h1 update (256 thr) =====
        if (tid < 256) {
            int m = tid >> 7, i = tid & 127;
            float gir = sbih1[i], giz = sbih1[i + 128], gin = sbih1[i + 256];
#pragma unroll
            for (int ks = 0; ks < 8; ks++) {
                int pb = (ks * 2 + m) * 392;
                gir += pgC[pb + i];
                giz += pgC[pb + i + 128];
                gin += pgC[pb + i + 256];
            }
            float ghr = sbhh1[i], ghz = sbhh1[i + 128], ghn = sbhh1[i + 256];
#pragma unroll
            for (int ks = 0; ks < 4; ks++) {
                int pb = (ks * 2 + m) * 392;
                ghr += pgB[pb + i];
                ghz += pgB[pb + i + 128];
                ghn += pgB[pb + i + 256];
            }
            float rr = 1.0f / (1.0f + expf(-(gir + ghr)));
            float zz = 1.0f / (1.0f + expf(-(giz + ghz)));
            float nn = tanhf(gin + rr * ghn);
            h1s[m * 132 + i] = (1.0f - zz) * nn + zz * h1s[m * 132 + i];
        }
        __syncthreads();

        // ===== phase E: logits partials (200 thr) =====
        if (tid < 200) {
            int ks = tid / 100, n = tid - ks * 100;
            int kk0p = ks * 64;
            const float* Zp = &Zs[n * 132 + kk0p];
            const float* hp = &h1s[kk0p];
            float a0 = 0.f, a1 = 0.f;
#pragma unroll 4
            for (int q = 0; q < 16; q++) {
                float4 z4 = *(const float4*)(Zp + 4 * q);
                float4 hA = *(const float4*)(hp + 4 * q);
                float4 hB = *(const float4*)(hp + 132 + 4 * q);
                a0 += hA.x * z4.x; a0 += hA.y * z4.y; a0 += hA.z * z4.z; a0 += hA.w * z4.w;
                a1 += hB.x * z4.x; a1 += hB.y * z4.y; a1 += hB.z * z4.z; a1 += hB.w * z4.w;
            }
            pl[(0 * 2 + ks) * 100 + n] = a0;
            pl[(1 * 2 + ks) * 100 + n] = a1;
        }
        __syncthreads();

        // ===== phase F: softmax stats + selection (wave0: sample, wave1: greedy) =====
        if (tid < 128) {
            const int m = tid >> 6, lane = tid & 63;
            float v0, v1 = -__builtin_inff();
            v0 = (pl[(m * 2 + 0) * 100 + lane] + pl[(m * 2 + 1) * 100 + lane]) * SCALEF;
            if (lane + 64 < NN)
                v1 = (pl[(m * 2 + 0) * 100 + lane + 64] + pl[(m * 2 + 1) * 100 + lane + 64]) * SCALEF;
            float mx = fmaxf(v0, v1);
            for (int off = 32; off > 0; off >>= 1) mx = fmaxf(mx, __shfl_xor(mx, off));
            float e = expf(v0 - mx) + ((lane + 64 < NN) ? expf(v1 - mx) : 0.0f);
            for (int off = 32; off > 0; off >>= 1) e += __shfl_xor(e, off);
            float a0 = v0, a1 = v1;
            if (m == 0) {
                a0 += gum[lane];
                if (lane + 64 < NN) a1 += gum[lane + 64];
            }
            float bv; int bi;
            if (a1 > a0) { bv = a1; bi = lane + 64; } else { bv = a0; bi = lane; }
            for (int off = 32; off > 0; off >>= 1) {
                float ov = __shfl_xor(bv, off);
                int   oi = __shfl_xor(bi, off);
                if (ov > bv || (ov == bv && oi < bi)) { bv = ov; bi = oi; }
            }
            int ind = bi;
            float la = __shfl(v0, ind & 63);
            float lb = __shfl(v1, ind & 63);
            float lv = (ind < 64) ? la : lb;
            if (lane == 0) {
                if (m == 0) out[O0 + b * (NN - 1) + t] = lv - mx - logf(e);
                else        out[O4 + (size_t)b * NN * NN + lastm * NN + ind] = 1.0f;
                s_ind2[m] = ind;
            }
            dist += dis[b * NN * NN + lastm * NN + ind];
            lastm = ind;
        }
        __syncthreads();
    }

    if (tid == 0)  out[O1 + b] = dist;
    if (tid == 64) out[O2 + b] = dist;
}

// ---------------- fallback decoder v4 (round-4 verified, 771 us) ----------------
__global__ __launch_bounds__(512, 2) void k_decode4(
    const float* __restrict__ P0, const float* __restrict__ Z,
    const float* __restrict__ dis,
    const float* __restrict__ Wih, const float* __restrict__ Whh,
    const float* __restrict__ bih, const float* __restrict__ bhh,
    float* __restrict__ out) {
    __shared__ float Zs[NN * 132];
    __shared__ float h0s[2 * 132], h1s[2 * 132];
    __shared__ float gi0s[2 * 384];
    __shared__ float pgA[2 * 2 * 392];
    __shared__ float pgB[2 * 2 * 392];
    __shared__ float pgC[4 * 2 * 392];
    __shared__ float sbhh0[T3], sbih1[T3], sbhh1[T3];
    __shared__ float pl[2 * 2 * 100];
    __shared__ float gum[128];
    __shared__ int s_ind2[2];

    const int tid = threadIdx.x;
    const int b = blockIdx.x;
    const float* __restrict__ Wih1 = Wih + 128 * T3;

    for (int i4 = tid; i4 < NN * 32; i4 += 512) {
        int r = i4 >> 5, c4 = (i4 & 31) * 4;
        *(float4*)&Zs[r * 132 + c4] = *(const float4*)&Z[(b * NN + r) * 128 + c4];
    }
    if (tid < T3) {
        sbhh0[tid] = bhh[tid];
        sbih1[tid] = bih[T3 + tid];
        sbhh1[tid] = bhh[T3 + tid];
    }
    if (tid < 256) {
        int m = tid >> 7, i = tid & 127;
        h0s[m * 132 + i] = 0.0f;
        h1s[m * 132 + i] = 0.0f;
    }
    if (tid == 0) { s_ind2[0] = 0; s_ind2[1] = 0; }

    unsigned kk0, kk1;
    tf2x32(0u, 42u, 0u, 0u, kk0, kk1);

    int lastm = 0;
    float dist = 0.0f;
    __syncthreads();

    for (int t = 0; t < NN - 1; t++) {
        if (tid < 384) {
            const int unit = tid / 192;
            const int r = tid - unit * 192;
            const int ks = r / 96, j4 = r - ks * 96;
            const int j0 = j4 * 4, k0 = ks * 64;
            const float* W = Whh + unit * (128 * T3) + (size_t)k0 * T3 + j0;
            const float* hp = ((unit == 0) ? h0s : h1s) + k0;
            float* pg = (unit == 0) ? pgA : pgB;
            matvec_tile4(W, hp, 16,
                         &pg[(ks * 2 + 0) * 392 + j0],
                         &pg[(ks * 2 + 1) * 392 + j0]);
        } else {
            int u = tid - 384;
            int l0 = s_ind2[0], l1 = s_ind2[1];
#pragma unroll
            for (int q = 0; q < 6; q++) {
                int f = u + 128 * q;
                int m = (f >= 384) ? 1 : 0;
                int j = f - m * 384;
                gi0s[f] = P0[(size_t)(b * NN + (m ? l1 : l0)) * T3 + j];
            }
            unsigned sk0, sk1, nk0, nk1;
            tf2x32(kk0, kk1, 0u, 1u, sk0, sk1);
            tf2x32(kk0, kk1, 0u, 0u, nk0, nk1);
            kk0 = nk0; kk1 = nk1;
            if (u < NN) gum[u] = gumbel_f(sk0, sk1, (unsigned)(b * NN + u));
        }
        __syncthreads();

        if (tid < 256) {
            int m = tid >> 7, i = tid & 127;
            float ghr = pgA[(0 * 2 + m) * 392 + i]       + pgA[(1 * 2 + m) * 392 + i]       + sbhh0[i];
            float ghz = pgA[(0 * 2 + m) * 392 + i + 128] + pgA[(1 * 2 + m) * 392 + i + 128] + sbhh0[i + 128];
            float ghn = pgA[(0 * 2 + m) * 392 + i + 256] + pgA[(1 * 2 + m) * 392 + i + 256] + sbhh0[i + 256];
            float rr = 1.0f / (1.0f + expf(-(gi0s[m * 384 + i] + ghr)));
            float zz = 1.0f / (1.0f + expf(-(gi0s[m * 384 + i + 128] + ghz)));
            float nn = tanhf(gi0s[m * 384 + i + 256] + rr * ghn);
            h0s[m * 132 + i] = (1.0f - zz) * nn + zz * h0s[m * 132 + i];
        }
        __syncthreads();

        if (tid < 384) {
            const int ks = tid / 96, j4 = tid - ks * 96;
            const int j0 = j4 * 4, k0 = ks * 32;
            const float* W = Wih1 + (size_t)k0 * T3 + j0;
            matvec_tile4(W, h0s + k0, 8,
                         &pgC[(ks * 2 + 0) * 392 + j0],
                         &pgC[(ks * 2 + 1) * 392 + j0]);
        }
        __syncthreads();

        if (tid < 256) {
            int m = tid >> 7, i = tid & 127;
            float gir = sbih1[i], giz = sbih1[i + 128], gin = sbih1[i + 256];
#pragma unroll
            for (int ks = 0; ks < 4; ks++) {
                int pb = (ks * 2 + m) * 392;
                gir += pgC[pb + i];
                giz += pgC[pb + i + 128];
                gin += pgC[pb + i + 256];
            }
            float ghr = pgB[(0 * 2 + m) * 392 + i]       + pgB[(1 * 2 + m) * 392 + i]       + sbhh1[i];
            float ghz = pgB[(0 * 2 + m) * 392 + i + 128] + pgB[(1 * 2 + m) * 392 + i + 128] + sbhh1[i + 128];
            float ghn = pgB[(0 * 2 + m) * 392 + i + 256] + pgB[(1 * 2 + m) * 392 + i + 256] + sbhh1[i + 256];
            float rr = 1.0f / (1.0f + expf(-(gir + ghr)));
            float zz = 1.0f / (1.0f + expf(-(giz + ghz)));
            float nn = tanhf(gin + rr * ghn);
            h1s[m * 132 + i] = (1.0f - zz) * nn + zz * h1s[m * 132 + i];
        }
        __syncthreads();

        if (tid < 200) {
            int ks = tid / 100, n = tid - ks * 100;
            int kk0p = ks * 64;
            const float* Zp = &Zs[n * 132 + kk0p];
            const float* hp = &h1s[kk0p];
            float a0 = 0.f, a1 = 0.f;
#pragma unroll 4
            for (int q = 0; q < 16; q++) {
                float4 z4 = *(const float4*)(Zp + 4 * q);
                float4 hA = *(const float4*)(hp + 4 * q);
                float4 hB = *(const float4*)(hp + 132 + 4 * q);
                a0 += hA.x * z4.x; a0 += hA.y * z4.y; a0 += hA.z * z4.z; a0 += hA.w * z4.w;
                a1 += hB.x * z4.x; a1 += hB.y * z4.y; a1 += hB.z * z4.z; a1 += hB.w * z4.w;
            }
            pl[(0 * 2 + ks) * 100 + n] = a0;
            pl[(1 * 2 + ks) * 100 + n] = a1;
        }
        __syncthreads();

        if (tid < 128) {
            const int m = tid >> 6, lane = tid & 63;
            float v0, v1 = -__builtin_inff();
            v0 = (pl[(m * 2 + 0) * 100 + lane] + pl[(m * 2 + 1) * 100 + lane]) * SCALEF;
            if (lane + 64 < NN)
                v1 = (pl[(m * 2 + 0) * 100 + lane + 64] + pl[(m * 2 + 1) * 100 + lane + 64]) * SCALEF;
            float mx = fmaxf(v0, v1);
            for (int off = 32; off > 0; off >>= 1) mx = fmaxf(mx, __shfl_xor(mx, off));
            float e = expf(v0 - mx) + ((lane + 64 < NN) ? expf(v1 - mx) : 0.0f);
            for (int off = 32; off > 0; off >>= 1) e += __shfl_xor(e, off);
            float a0 = v0, a1 = v1;
            if (m == 0) {
                a0 += gum[lane];
                if (lane + 64 < NN) a1 += gum[lane + 64];
            }
            float bv; int bi;
            if (a1 > a0) { bv = a1; bi = lane + 64; } else { bv = a0; bi = lane; }
            for (int off = 32; off > 0; off >>= 1) {
                float ov = __shfl_xor(bv, off);
                int   oi = __shfl_xor(bi, off);
                if (ov > bv || (ov == bv && oi < bi)) { bv = ov; bi = oi; }
            }
            int ind = bi;
            float la = __shfl(v0, ind & 63);
            float lb = __shfl(v1, ind & 63);
            float lv = (ind < 64) ? la : lb;
            if (lane == 0) {
                if (m == 0) out[O0 + b * (NN - 1) + t] = lv - mx - logf(e);
                else        out[O4 + (size_t)b * NN * NN + lastm * NN + ind] = 1.0f;
                s_ind2[m] = ind;
            }
            dist += dis[b * NN * NN + lastm * NN + ind];
            lastm = ind;
        }
        __syncthreads();
    }

    if (tid == 0)  out[O1 + b] = dist;
    if (tid == 64) out[O2 + b] = dist;
}

// ---------------- host launcher ----------------
extern "C" void kernel_launch(void* const* d_in, const int* in_sizes, int n_in,
                              void* d_out, int out_size, void* d_ws, size_t ws_size,
                              hipStream_t stream) {
    (void)in_sizes; (void)n_in; (void)out_size;
    const float* node   = (const float*)d_in[0];
    const float* demand = (const float*)d_in[1];
    const float* dis    = (const float*)d_in[2];
    const float* Wn0    = (const float*)d_in[3];
    const float* bn0    = (const float*)d_in[4];
    const float* Ws     = (const float*)d_in[5];
    const float* Wngh   = (const float*)d_in[6];
    const float* We     = (const float*)d_in[7];
    const float* be     = (const float*)d_in[8];
    const float* Wih    = (const float*)d_in[9];
    const float* Whh    = (const float*)d_in[10];
    const float* bih    = (const float*)d_in[11];
    const float* bhh    = (const float*)d_in[12];
    const float* Wq     = (const float*)d_in[13];
    const float* Wc     = (const float*)d_in[14];
    const float* bc     = (const float*)d_in[15];
    float* out = (float*)d_out;
    float* ws  = (float*)d_ws;

    float* hA  = ws;
    float* hB  = ws + 819200;
    float* hw  = ws + 1638400;      // hw during encoder; Z after
    float* A   = ws + 2457600;
    float* P0  = ws + 2457600;      // overlays A after encoder
    float* WqT = ws + 4915200;
    const size_t need_bytes = (size_t)4931584 * 4;
    const bool big_ws = ws_size >= need_bytes;

    hipLaunchKernelGGL(k_embed, dim3(3200), dim3(256), 0, stream, node, demand, Wn0, bn0, hA);
    hipLaunchKernelGGL(k_adj, dim3(6400), dim3(64), 0, stream, dis, A);

    float* cur = hA;
    float* nxt = hB;
    for (int l = 0; l < 3; l++) {
        hipLaunchKernelGGL(k_hw, dim3(800), dim3(256), 0, stream, cur, Wngh + l * 16384, hw);
        hipLaunchKernelGGL(k_agg, dim3(1600), dim3(256), 0, stream, cur, Ws + l * 16384, A, hw, nxt);
        float* tswap = cur; cur = nxt; nxt = tswap;
    }

    hipLaunchKernelGGL(k_predict, dim3(2500), dim3(256), 0, stream, dis, We, be, Wc, bc, out + O3);
    hipLaunchKernelGGL(k_zero, dim3(2500), dim3(256), 0, stream, out + O4, BB * NN * NN);

    hipLaunchKernelGGL(k_transpose128, dim3(64), dim3(256), 0, stream, Wq, WqT);
    hipLaunchKernelGGL(k_hw, dim3(800), dim3(256), 0, stream, cur, WqT, hw);   // Z
    hipLaunchKernelGGL(k_mm384, dim3(800, 3), dim3(256), 0, stream, cur, Wih, bih, P0);
    if (big_ws) {
        hipLaunchKernelGGL(k_decode8, dim3(64), dim3(1024), 0, stream,
                           P0, hw, dis, Wih, Whh, bih, bhh, out);
    } else {
        hipLaunchKernelGGL(k_decode4, dim3(64), dim3(512), 0, stream,
                           P0, hw, dis, Wih, Whh, bih, bhh, out);
    }
}

// Round 9
// 979.565 us; speedup vs baseline: 2.1144x; 1.1737x over previous
//
#include <hip/hip_runtime.h>
#include <math.h>

// Problem constants
#define BB 64
#define NN 100
#define HH 128
#define T3 384

// Output layout (floats, concatenated in return order)
#define O0 0            // sample_logprob [64,99]
#define O1 6336         // sample_distance [64,1]
#define O2 6400         // greedy_distance [64,1]
#define O3 6464         // predict_matrix [64,100,100,2]
#define O4 1286464      // greedy_solution_matrix [64,100,100]

#define TINYF 1.17549435e-38f
#define SCALEF 0.08838834764831845f

// ---------------- threefry2x32 (exact JAX implementation) ----------------
__device__ __forceinline__ unsigned rotl32(unsigned x, int d) {
    return (x << d) | (x >> (32 - d));
}

__device__ __forceinline__ void tf2x32(unsigned ks0, unsigned ks1,
                                       unsigned x0, unsigned x1,
                                       unsigned& o0, unsigned& o1) {
    unsigned ks2 = ks0 ^ ks1 ^ 0x1BD11BDAu;
    x0 += ks0; x1 += ks1;
    x0 += x1; x1 = rotl32(x1, 13); x1 ^= x0;
    x0 += x1; x1 = rotl32(x1, 15); x1 ^= x0;
    x0 += x1; x1 = rotl32(x1, 26); x1 ^= x0;
    x0 += x1; x1 = rotl32(x1, 6);  x1 ^= x0;
    x0 += ks1; x1 += ks2 + 1u;
    x0 += x1; x1 = rotl32(x1, 17); x1 ^= x0;
    x0 += x1; x1 = rotl32(x1, 29); x1 ^= x0;
    x0 += x1; x1 = rotl32(x1, 16); x1 ^= x0;
    x0 += x1; x1 = rotl32(x1, 24); x1 ^= x0;
    x0 += ks2; x1 += ks0 + 2u;
    x0 += x1; x1 = rotl32(x1, 13); x1 ^= x0;
    x0 += x1; x1 = rotl32(x1, 15); x1 ^= x0;
    x0 += x1; x1 = rotl32(x1, 26); x1 ^= x0;
    x0 += x1; x1 = rotl32(x1, 6);  x1 ^= x0;
    x0 += ks0; x1 += ks1 + 3u;
    x0 += x1; x1 = rotl32(x1, 17); x1 ^= x0;
    x0 += x1; x1 = rotl32(x1, 29); x1 ^= x0;
    x0 += x1; x1 = rotl32(x1, 16); x1 ^= x0;
    x0 += x1; x1 = rotl32(x1, 24); x1 ^= x0;
    x0 += ks1; x1 += ks2 + 4u;
    x0 += x1; x1 = rotl32(x1, 13); x1 ^= x0;
    x0 += x1; x1 = rotl32(x1, 15); x1 ^= x0;
    x0 += x1; x1 = rotl32(x1, 26); x1 ^= x0;
    x0 += x1; x1 = rotl32(x1, 6);  x1 ^= x0;
    x0 += ks2; x1 += ks0 + 5u;
    o0 = x0; o1 = x1;
}

__device__ __forceinline__ float gumbel_f(unsigned k0, unsigned k1, unsigned f) {
    unsigned o0, o1;
    tf2x32(k0, k1, 0u, f, o0, o1);
    unsigned bits = o0 ^ o1;
    float u01 = __uint_as_float((bits >> 9) | 0x3F800000u) - 1.0f;
    float u = fmaxf(TINYF, u01 * (1.0f - TINYF) + TINYF);
    return -logf(-logf(u));
}

// ---------------- fused embed + adjacency softmax ----------------
// grid 4800: blocks [0,3200) embed h0; [3200,4800) adj softmax (4 rows/block, 1 wave each)
__global__ void k_embed_adj(const float* __restrict__ node, const float* __restrict__ demand,
                            const float* __restrict__ Wn0, const float* __restrict__ bn0,
                            const float* __restrict__ dis,
                            float* __restrict__ h, float* __restrict__ A) {
    int bid = blockIdx.x, tid = threadIdx.x;
    if (bid < 3200) {
        int idx = bid * 256 + tid;
        int r = idx >> 7, c = idx & 127;
        float v = node[r * 2] * Wn0[c] + node[r * 2 + 1] * Wn0[128 + c]
                + demand[r] * Wn0[256 + c] + bn0[c];
        h[idx] = fmaxf(v, 0.0f);
    } else {
        int row = (bid - 3200) * 4 + (tid >> 6);
        int l = tid & 63;
        const float* d = dis + row * NN;
        float v0 = -d[l];
        float v1 = (l + 64 < NN) ? -d[l + 64] : -__builtin_inff();
        float m = fmaxf(v0, v1);
        for (int off = 32; off > 0; off >>= 1) m = fmaxf(m, __shfl_xor(m, off));
        float e0 = expf(v0 - m);
        float e1 = (l + 64 < NN) ? expf(v1 - m) : 0.0f;
        float s = e0 + e1;
        for (int off = 32; off > 0; off >>= 1) s += __shfl_xor(s, off);
        float inv = 1.0f / s;
        A[row * NN + l] = e0 * inv;
        if (l + 64 < NN) A[row * NN + l + 64] = e1 * inv;
    }
}

// out[6400x128] = h @ W[128x128]; 16 rows/block (identical per-output sum order to k_hw)
__global__ void k_hw16(const float* __restrict__ h, const float* __restrict__ W,
                       float* __restrict__ out) {
    __shared__ float hs[16 * 128];
    int block_row = blockIdx.x * 16;
    int tid = threadIdx.x;
    int col = tid & 127;
    int rg = tid >> 7;
    for (int i = tid; i < 16 * 128; i += 256) hs[i] = h[block_row * 128 + i];
    __syncthreads();
    float acc[8] = {0.f, 0.f, 0.f, 0.f, 0.f, 0.f, 0.f, 0.f};
    for (int k = 0; k < 128; k++) {
        float w = W[k * 128 + col];
#pragma unroll
        for (int r = 0; r < 8; r++) acc[r] += hs[(rg + 2 * r) * 128 + k] * w;
    }
#pragma unroll
    for (int r = 0; r < 8; r++)
        out[(block_row + rg + 2 * r) * 128 + col] = acc[r];
}

// fused Z (h@WqT) + P0 (h@Wih0+bih0); grid (400, 4): y==0 -> Z, y in 1..3 -> P0 col-block
__global__ void k_zp(const float* __restrict__ h, const float* __restrict__ WqT,
                     const float* __restrict__ Wih, const float* __restrict__ bih,
                     float* __restrict__ Z, float* __restrict__ P0) {
    __shared__ float hs[16 * 128];
    int block_row = blockIdx.x * 16;
    int tid = threadIdx.x;
    int c = tid & 127;
    int rg = tid >> 7;
    int y = blockIdx.y;
    for (int i = tid; i < 16 * 128; i += 256) hs[i] = h[block_row * 128 + i];
    __syncthreads();
    float acc[8] = {0.f, 0.f, 0.f, 0.f, 0.f, 0.f, 0.f, 0.f};
    if (y == 0) {
        for (int k = 0; k < 128; k++) {
            float w = WqT[k * 128 + c];
#pragma unroll
            for (int r = 0; r < 8; r++) acc[r] += hs[(rg + 2 * r) * 128 + k] * w;
        }
#pragma unroll
        for (int r = 0; r < 8; r++)
            Z[(block_row + rg + 2 * r) * 128 + c] = acc[r];
    } else {
        int col = (y - 1) * 128 + c;
        for (int k = 0; k < 128; k++) {
            float w = Wih[k * 384 + col];
#pragma unroll
            for (int r = 0; r < 8; r++) acc[r] += hs[(rg + 2 * r) * 128 + k] * w;
        }
        float bb = bih[col];
#pragma unroll
        for (int r = 0; r < 8; r++)
            P0[(size_t)(block_row + rg + 2 * r) * 384 + col] = acc[r] + bb;
    }
}

__global__ void k_transpose128(const float* __restrict__ Wq, float* __restrict__ WqT) {
    int i = blockIdx.x * 256 + threadIdx.x;
    if (i >= 128 * 128) return;
    int k = i >> 7, c = i & 127;
    WqT[k * 128 + c] = Wq[c * 128 + k];
}

// h' = relu(h@Ws + A@hw); 10 rows/block (identical per-output sum order to k_agg)
__global__ void k_agg10(const float* __restrict__ h, const float* __restrict__ Ws,
                        const float* __restrict__ A, const float* __restrict__ hw,
                        float* __restrict__ out) {
    __shared__ float hs[10 * 128];
    __shared__ float As[10 * 100];
    int b = blockIdx.x / 10;
    int i0 = (blockIdx.x % 10) * 10;
    int tid = threadIdx.x;
    int col = tid & 127;
    int rg = tid >> 7;
    int rowbase = b * NN + i0;
    for (int i = tid; i < 10 * 128; i += 256) hs[i] = h[rowbase * 128 + i];
    for (int i = tid; i < 10 * 100; i += 256) As[i] = A[rowbase * 100 + i];
    __syncthreads();
    float acc[5] = {0.f, 0.f, 0.f, 0.f, 0.f};
    for (int k = 0; k < 128; k++) {
        float w = Ws[k * 128 + col];
#pragma unroll
        for (int r = 0; r < 5; r++) acc[r] += hs[(rg + 2 * r) * 128 + k] * w;
    }
    const float* hwb = hw + b * NN * 128;
    for (int j = 0; j < NN; j++) {
        float v = hwb[j * 128 + col];
#pragma unroll
        for (int r = 0; r < 5; r++) acc[r] += As[(rg + 2 * r) * 100 + j] * v;
    }
#pragma unroll
    for (int r = 0; r < 5; r++)
        out[(rowbase + rg + 2 * r) * 128 + col] = fmaxf(acc[r], 0.0f);
}

// fused predict (2 pos/thread, blocks [0,1250)) + zero of solution matrix (blocks [1250,1875))
__global__ void k_predict_zero(const float* __restrict__ dis, const float* __restrict__ We,
                               const float* __restrict__ be, const float* __restrict__ Wc,
                               const float* __restrict__ bc, float* __restrict__ out3,
                               float* __restrict__ zp) {
    int bid = blockIdx.x, tid = threadIdx.x;
    if (bid >= 1250) {
        int i = (bid - 1250) * 256 + tid;   // 625 blocks * 256 = 160000 float4 = 640000 floats
        float4 z; z.x = 0.f; z.y = 0.f; z.z = 0.f; z.w = 0.f;
        ((float4*)zp)[i] = z;
        return;
    }
    __shared__ float sWe[128], sbe[128], sc0[128], sc1[128];
    if (tid < 128) {
        sWe[tid] = We[tid];
        sbe[tid] = be[tid];
        sc0[tid] = Wc[tid * 2];
        sc1[tid] = Wc[tid * 2 + 1];
    }
    __syncthreads();
    float b0 = bc[0], b1 = bc[1];
    int p0 = bid * 512 + tid, p1 = p0 + 256;
    float d0 = dis[p0], d1 = dis[p1];
    float a00 = b0, a01 = b1, a10 = b0, a11 = b1;
    for (int k = 0; k < 128; k++) {
        float we = sWe[k], bbe = sbe[k], c0 = sc0[k], c1 = sc1[k];
        float e0 = fmaxf(d0 * we + bbe, 0.0f);
        float e1 = fmaxf(d1 * we + bbe, 0.0f);
        a00 += e0 * c0; a01 += e0 * c1;
        a10 += e1 * c0; a11 += e1 * c1;
    }
    {
        float m = fmaxf(a00, a01);
        float q0 = expf(a00 - m), q1 = expf(a01 - m);
        float inv = 1.0f / (q0 + q1);
        out3[p0 * 2] = q0 * inv;
        out3[p0 * 2 + 1] = q1 * inv;
    }
    {
        float m = fmaxf(a10, a11);
        float q0 = expf(a10 - m), q1 = expf(a11 - m);
        float inv = 1.0f / (q0 + q1);
        out3[p1 * 2] = q0 * inv;
        out3[p1 * 2 + 1] = q1 * inv;
    }
}

// ---------------- shared matvec tile (spill-proof, ~40 VGPR) ----------------
__device__ __forceinline__ void matvec_tile4(const float* __restrict__ W,   // &W[k0*384 + j0]
                                             const float* __restrict__ hp,  // &h[k0]; modes +0,+132
                                             int nk4,
                                             float* __restrict__ pg0,
                                             float* __restrict__ pg1) {
    float a00 = 0.f, a01 = 0.f, a02 = 0.f, a03 = 0.f;
    float a10 = 0.f, a11 = 0.f, a12 = 0.f, a13 = 0.f;
#pragma unroll 4
    for (int k4 = 0; k4 < nk4; ++k4) {
        float4 hA = *(const float4*)(hp + 4 * k4);
        float4 hB = *(const float4*)(hp + 132 + 4 * k4);
        const float* Wk = W + (size_t)(4 * k4) * T3;
        float4 w0 = *(const float4*)(Wk);
        float4 w1 = *(const float4*)(Wk + T3);
        float4 w2 = *(const float4*)(Wk + 2 * T3);
        float4 w3 = *(const float4*)(Wk + 3 * T3);
        a00 += hA.x * w0.x; a01 += hA.x * w0.y; a02 += hA.x * w0.z; a03 += hA.x * w0.w;
        a10 += hB.x * w0.x; a11 += hB.x * w0.y; a12 += hB.x * w0.z; a13 += hB.x * w0.w;
        a00 += hA.y * w1.x; a01 += hA.y * w1.y; a02 += hA.y * w1.z; a03 += hA.y * w1.w;
        a10 += hB.y * w1.x; a11 += hB.y * w1.y; a12 += hB.y * w1.z; a13 += hB.y * w1.w;
        a00 += hA.z * w2.x; a01 += hA.z * w2.y; a02 += hA.z * w2.z; a03 += hA.z * w2.w;
        a10 += hB.z * w2.x; a11 += hB.z * w2.y; a12 += hB.z * w2.z; a13 += hB.z * w2.w;
        a00 += hA.w * w3.x; a01 += hA.w * w3.y; a02 += hA.w * w3.z; a03 += hA.w * w3.w;
        a10 += hB.w * w3.x; a11 += hB.w * w3.y; a12 += hB.w * w3.z; a13 += hB.w * w3.w;
    }
    float4 o;
    o.x = a00; o.y = a01; o.z = a02; o.w = a03;
    *(float4*)pg0 = o;
    o.x = a10; o.y = a11; o.z = a12; o.w = a13;
    *(float4*)pg1 = o;
}

// ---------------- decoder v4 (round-4 verified, 771 us, VGPR 92, no spill) ----------------
__global__ __launch_bounds__(512, 2) void k_decode4(
    const float* __restrict__ P0, const float* __restrict__ Z,
    const float* __restrict__ dis,
    const float* __restrict__ Wih, const float* __restrict__ Whh,
    const float* __restrict__ bih, const float* __restrict__ bhh,
    float* __restrict__ out) {
    __shared__ float Zs[NN * 132];
    __shared__ float h0s[2 * 132], h1s[2 * 132];
    __shared__ float gi0s[2 * 384];
    __shared__ float pgA[2 * 2 * 392];
    __shared__ float pgB[2 * 2 * 392];
    __shared__ float pgC[4 * 2 * 392];
    __shared__ float sbhh0[T3], sbih1[T3], sbhh1[T3];
    __shared__ float pl[2 * 2 * 100];
    __shared__ float gum[128];
    __shared__ int s_ind2[2];

    const int tid = threadIdx.x;
    const int b = blockIdx.x;
    const float* __restrict__ Wih1 = Wih + 128 * T3;

    for (int i4 = tid; i4 < NN * 32; i4 += 512) {
        int r = i4 >> 5, c4 = (i4 & 31) * 4;
        *(float4*)&Zs[r * 132 + c4] = *(const float4*)&Z[(b * NN + r) * 128 + c4];
    }
    if (tid < T3) {
        sbhh0[tid] = bhh[tid];
        sbih1[tid] = bih[T3 + tid];
        sbhh1[tid] = bhh[T3 + tid];
    }
    if (tid < 256) {
        int m = tid >> 7, i = tid & 127;
        h0s[m * 132 + i] = 0.0f;
        h1s[m * 132 + i] = 0.0f;
    }
    if (tid == 0) { s_ind2[0] = 0; s_ind2[1] = 0; }

    unsigned kk0, kk1;
    tf2x32(0u, 42u, 0u, 0u, kk0, kk1);

    int lastm = 0;
    float dist = 0.0f;
    __syncthreads();

    for (int t = 0; t < NN - 1; t++) {
        if (tid < 384) {
            const int unit = tid / 192;
            const int r = tid - unit * 192;
            const int ks = r / 96, j4 = r - ks * 96;
            const int j0 = j4 * 4, k0 = ks * 64;
            const float* W = Whh + unit * (128 * T3) + (size_t)k0 * T3 + j0;
            const float* hp = ((unit == 0) ? h0s : h1s) + k0;
            float* pg = (unit == 0) ? pgA : pgB;
            matvec_tile4(W, hp, 16,
                         &pg[(ks * 2 + 0) * 392 + j0],
                         &pg[(ks * 2 + 1) * 392 + j0]);
        } else {
            int u = tid - 384;
            int l0 = s_ind2[0], l1 = s_ind2[1];
#pragma unroll
            for (int q = 0; q < 6; q++) {
                int f = u + 128 * q;
                int m = (f >= 384) ? 1 : 0;
                int j = f - m * 384;
                gi0s[f] = P0[(size_t)(b * NN + (m ? l1 : l0)) * T3 + j];
            }
            unsigned sk0, sk1, nk0, nk1;
            tf2x32(kk0, kk1, 0u, 1u, sk0, sk1);
            tf2x32(kk0, kk1, 0u, 0u, nk0, nk1);
            kk0 = nk0; kk1 = nk1;
            if (u < NN) gum[u] = gumbel_f(sk0, sk1, (unsigned)(b * NN + u));
        }
        __syncthreads();

        if (tid < 256) {
            int m = tid >> 7, i = tid & 127;
            float ghr = pgA[(0 * 2 + m) * 392 + i]       + pgA[(1 * 2 + m) * 392 + i]       + sbhh0[i];
            float ghz = pgA[(0 * 2 + m) * 392 + i + 128] + pgA[(1 * 2 + m) * 392 + i + 128] + sbhh0[i + 128];
            float ghn = pgA[(0 * 2 + m) * 392 + i + 256] + pgA[(1 * 2 + m) * 392 + i + 256] + sbhh0[i + 256];
            float rr = 1.0f / (1.0f + expf(-(gi0s[m * 384 + i] + ghr)));
            float zz = 1.0f / (1.0f + expf(-(gi0s[m * 384 + i + 128] + ghz)));
            float nn = tanhf(gi0s[m * 384 + i + 256] + rr * ghn);
            h0s[m * 132 + i] = (1.0f - zz) * nn + zz * h0s[m * 132 + i];
        }
        __syncthreads();

        if (tid < 384) {
            const int ks = tid / 96, j4 = tid - ks * 96;
            const int j0 = j4 * 4, k0 = ks * 32;
            const float* W = Wih1 + (size_t)k0 * T3 + j0;
            matvec_tile4(W, h0s + k0, 8,
                         &pgC[(ks * 2 + 0) * 392 + j0],
                         &pgC[(ks * 2 + 1) * 392 + j0]);
        }
        __syncthreads();

        if (tid < 256) {
            int m = tid >> 7, i = tid & 127;
            float gir = sbih1[i], giz = sbih1[i + 128], gin = sbih1[i + 256];
#pragma unroll
            for (int ks = 0; ks < 4; ks++) {
                int pb = (ks * 2 + m) * 392;
                gir += pgC[pb + i];
                giz += pgC[pb + i + 128];
                gin += pgC[pb + i + 256];
            }
            float ghr = pgB[(0 * 2 + m) * 392 + i]       + pgB[(1 * 2 + m) * 392 + i]       + sbhh1[i];
            float ghz = pgB[(0 * 2 + m) * 392 + i + 128] + pgB[(1 * 2 + m) * 392 + i + 128] + sbhh1[i + 128];
            float ghn = pgB[(0 * 2 + m) * 392 + i + 256] + pgB[(1 * 2 + m) * 392 + i + 256] + sbhh1[i + 256];
            float rr = 1.0f / (1.0f + expf(-(gir + ghr)));
            float zz = 1.0f / (1.0f + expf(-(giz + ghz)));
            float nn = tanhf(gin + rr * ghn);
            h1s[m * 132 + i] = (1.0f - zz) * nn + zz * h1s[m * 132 + i];
        }
        __syncthreads();

        if (tid < 200) {
            int ks = tid / 100, n = tid - ks * 100;
            int kk0p = ks * 64;
            const float* Zp = &Zs[n * 132 + kk0p];
            const float* hp = &h1s[kk0p];
            float a0 = 0.f, a1 = 0.f;
#pragma unroll 4
            for (int q = 0; q < 16; q++) {
                float4 z4 = *(const float4*)(Zp + 4 * q);
                float4 hA = *(const float4*)(hp + 4 * q);
                float4 hB = *(const float4*)(hp + 132 + 4 * q);
                a0 += hA.x * z4.x; a0 += hA.y * z4.y; a0 += hA.z * z4.z; a0 += hA.w * z4.w;
                a1 += hB.x * z4.x; a1 += hB.y * z4.y; a1 += hB.z * z4.z; a1 += hB.w * z4.w;
            }
            pl[(0 * 2 + ks) * 100 + n] = a0;
            pl[(1 * 2 + ks) * 100 + n] = a1;
        }
        __syncthreads();

        if (tid < 128) {
            const int m = tid >> 6, lane = tid & 63;
            float v0, v1 = -__builtin_inff();
            v0 = (pl[(m * 2 + 0) * 100 + lane] + pl[(m * 2 + 1) * 100 + lane]) * SCALEF;
            if (lane + 64 < NN)
                v1 = (pl[(m * 2 + 0) * 100 + lane + 64] + pl[(m * 2 + 1) * 100 + lane + 64]) * SCALEF;
            float mx = fmaxf(v0, v1);
            for (int off = 32; off > 0; off >>= 1) mx = fmaxf(mx, __shfl_xor(mx, off));
            float e = expf(v0 - mx) + ((lane + 64 < NN) ? expf(v1 - mx) : 0.0f);
            for (int off = 32; off > 0; off >>= 1) e += __shfl_xor(e, off);
            float a0 = v0, a1 = v1;
            if (m == 0) {
                a0 += gum[lane];
                if (lane + 64 < NN) a1 += gum[lane + 64];
            }
            float bv; int bi;
            if (a1 > a0) { bv = a1; bi = lane + 64; } else { bv = a0; bi = lane; }
            for (int off = 32; off > 0; off >>= 1) {
                float ov = __shfl_xor(bv, off);
                int   oi = __shfl_xor(bi, off);
                if (ov > bv || (ov == bv && oi < bi)) { bv = ov; bi = oi; }
            }
            int ind = bi;
            float la = __shfl(v0, ind & 63);
            float lb = __shfl(v1, ind & 63);
            float lv = (ind < 64) ? la : lb;
            if (lane == 0) {
                if (m == 0) out[O0 + b * (NN - 1) + t] = lv - mx - logf(e);
                else        out[O4 + (size_t)b * NN * NN + lastm * NN + ind] = 1.0f;
                s_ind2[m] = ind;
            }
            dist += dis[b * NN * NN + lastm * NN + ind];
            lastm = ind;
        }
        __syncthreads();
    }

    if (tid == 0)  out[O1 + b] = dist;
    if (tid == 64) out[O2 + b] = dist;
}

// ---------------- host launcher ----------------
extern "C" void kernel_launch(void* const* d_in, const int* in_sizes, int n_in,
                              void* d_out, int out_size, void* d_ws, size_t ws_size,
                              hipStream_t stream) {
    (void)in_sizes; (void)n_in; (void)out_size; (void)ws_size;
    const float* node   = (const float*)d_in[0];
    const float* demand = (const float*)d_in[1];
    const float* dis    = (const float*)d_in[2];
    const float* Wn0    = (const float*)d_in[3];
    const float* bn0    = (const float*)d_in[4];
    const float* Ws     = (const float*)d_in[5];
    const float* Wngh   = (const float*)d_in[6];
    const float* We     = (const float*)d_in[7];
    const float* be     = (const float*)d_in[8];
    const float* Wih    = (const float*)d_in[9];
    const float* Whh    = (const float*)d_in[10];
    const float* bih    = (const float*)d_in[11];
    const float* bhh    = (const float*)d_in[12];
    const float* Wq     = (const float*)d_in[13];
    const float* Wc     = (const float*)d_in[14];
    const float* bc     = (const float*)d_in[15];
    float* out = (float*)d_out;
    float* ws  = (float*)d_ws;

    float* hA  = ws;                // 819200
    float* hB  = ws + 819200;       // 819200
    float* hw  = ws + 1638400;      // hw during encoder; Z after
    float* A   = ws + 2457600;      // A during encoder
    float* P0  = ws + 2457600;      // P0 overlays A after encoder
    float* WqT = ws + 4915200;      // 16384

    // predict + zero first (independent of encoder)
    hipLaunchKernelGGL(k_predict_zero, dim3(1875), dim3(256), 0, stream,
                       dis, We, be, Wc, bc, out + O3, out + O4);

    hipLaunchKernelGGL(k_embed_adj, dim3(4800), dim3(256), 0, stream,
                       node, demand, Wn0, bn0, dis, hA, A);

    float* cur = hA;
    float* nxt = hB;
    for (int l = 0; l < 3; l++) {
        hipLaunchKernelGGL(k_hw16, dim3(400), dim3(256), 0, stream, cur, Wngh + l * 16384, hw);
        hipLaunchKernelGGL(k_agg10, dim3(640), dim3(256), 0, stream, cur, Ws + l * 16384, A, hw, nxt);
        float* tswap = cur; cur = nxt; nxt = tswap;
    }
    // cur == hB holds the final encoder output

    hipLaunchKernelGGL(k_transpose128, dim3(64), dim3(256), 0, stream, Wq, WqT);
    hipLaunchKernelGGL(k_zp, dim3(400, 4), dim3(256), 0, stream, cur, WqT, Wih, bih, hw, P0);

    hipLaunchKernelGGL(k_decode4, dim3(64), dim3(512), 0, stream,
                       P0, hw, dis, Wih, Whh, bih, bhh, out);
}

// Round 10
// 923.361 us; speedup vs baseline: 2.2431x; 1.0609x over previous
//
#include <hip/hip_runtime.h>
#include <math.h>

// Problem constants
#define BB 64
#define NN 100
#define HH 128
#define T3 384

// Output layout (floats, concatenated in return order)
#define O0 0            // sample_logprob [64,99]
#define O1 6336         // sample_distance [64,1]
#define O2 6400         // greedy_distance [64,1]
#define O3 6464         // predict_matrix [64,100,100,2]
#define O4 1286464      // greedy_solution_matrix [64,100,100]

#define TINYF 1.17549435e-38f
#define SCALEF 0.08838834764831845f

// ---------------- threefry2x32 (exact JAX implementation) ----------------
__device__ __forceinline__ unsigned rotl32(unsigned x, int d) {
    return (x << d) | (x >> (32 - d));
}

__device__ __forceinline__ void tf2x32(unsigned ks0, unsigned ks1,
                                       unsigned x0, unsigned x1,
                                       unsigned& o0, unsigned& o1) {
    unsigned ks2 = ks0 ^ ks1 ^ 0x1BD11BDAu;
    x0 += ks0; x1 += ks1;
    x0 += x1; x1 = rotl32(x1, 13); x1 ^= x0;
    x0 += x1; x1 = rotl32(x1, 15); x1 ^= x0;
    x0 += x1; x1 = rotl32(x1, 26); x1 ^= x0;
    x0 += x1; x1 = rotl32(x1, 6);  x1 ^= x0;
    x0 += ks1; x1 += ks2 + 1u;
    x0 += x1; x1 = rotl32(x1, 17); x1 ^= x0;
    x0 += x1; x1 = rotl32(x1, 29); x1 ^= x0;
    x0 += x1; x1 = rotl32(x1, 16); x1 ^= x0;
    x0 += x1; x1 = rotl32(x1, 24); x1 ^= x0;
    x0 += ks2; x1 += ks0 + 2u;
    x0 += x1; x1 = rotl32(x1, 13); x1 ^= x0;
    x0 += x1; x1 = rotl32(x1, 15); x1 ^= x0;
    x0 += x1; x1 = rotl32(x1, 26); x1 ^= x0;
    x0 += x1; x1 = rotl32(x1, 6);  x1 ^= x0;
    x0 += ks0; x1 += ks1 + 3u;
    x0 += x1; x1 = rotl32(x1, 17); x1 ^= x0;
    x0 += x1; x1 = rotl32(x1, 29); x1 ^= x0;
    x0 += x1; x1 = rotl32(x1, 16); x1 ^= x0;
    x0 += x1; x1 = rotl32(x1, 24); x1 ^= x0;
    x0 += ks1; x1 += ks2 + 4u;
    x0 += x1; x1 = rotl32(x1, 13); x1 ^= x0;
    x0 += x1; x1 = rotl32(x1, 15); x1 ^= x0;
    x0 += x1; x1 = rotl32(x1, 26); x1 ^= x0;
    x0 += x1; x1 = rotl32(x1, 6);  x1 ^= x0;
    x0 += ks2; x1 += ks0 + 5u;
    o0 = x0; o1 = x1;
}

__device__ __forceinline__ float gumbel_f(unsigned k0, unsigned k1, unsigned f) {
    unsigned o0, o1;
    tf2x32(k0, k1, 0u, f, o0, o1);
    unsigned bits = o0 ^ o1;
    float u01 = __uint_as_float((bits >> 9) | 0x3F800000u) - 1.0f;
    float u = fmaxf(TINYF, u01 * (1.0f - TINYF) + TINYF);
    return -logf(-logf(u));
}

// ---------------- fused embed + adjacency softmax ----------------
__global__ void k_embed_adj(const float* __restrict__ node, const float* __restrict__ demand,
                            const float* __restrict__ Wn0, const float* __restrict__ bn0,
                            const float* __restrict__ dis,
                            float* __restrict__ h, float* __restrict__ A) {
    int bid = blockIdx.x, tid = threadIdx.x;
    if (bid < 3200) {
        int idx = bid * 256 + tid;
        int r = idx >> 7, c = idx & 127;
        float v = node[r * 2] * Wn0[c] + node[r * 2 + 1] * Wn0[128 + c]
                + demand[r] * Wn0[256 + c] + bn0[c];
        h[idx] = fmaxf(v, 0.0f);
    } else {
        int row = (bid - 3200) * 4 + (tid >> 6);
        int l = tid & 63;
        const float* d = dis + row * NN;
        float v0 = -d[l];
        float v1 = (l + 64 < NN) ? -d[l + 64] : -__builtin_inff();
        float m = fmaxf(v0, v1);
        for (int off = 32; off > 0; off >>= 1) m = fmaxf(m, __shfl_xor(m, off));
        float e0 = expf(v0 - m);
        float e1 = (l + 64 < NN) ? expf(v1 - m) : 0.0f;
        float s = e0 + e1;
        for (int off = 32; off > 0; off >>= 1) s += __shfl_xor(s, off);
        float inv = 1.0f / s;
        A[row * NN + l] = e0 * inv;
        if (l + 64 < NN) A[row * NN + l + 64] = e1 * inv;
    }
}

// out[6400x128] = h @ W[128x128]; 16 rows/block
__global__ void k_hw16(const float* __restrict__ h, const float* __restrict__ W,
                       float* __restrict__ out) {
    __shared__ float hs[16 * 128];
    int block_row = blockIdx.x * 16;
    int tid = threadIdx.x;
    int col = tid & 127;
    int rg = tid >> 7;
    for (int i = tid; i < 16 * 128; i += 256) hs[i] = h[block_row * 128 + i];
    __syncthreads();
    float acc[8] = {0.f, 0.f, 0.f, 0.f, 0.f, 0.f, 0.f, 0.f};
    for (int k = 0; k < 128; k++) {
        float w = W[k * 128 + col];
#pragma unroll
        for (int r = 0; r < 8; r++) acc[r] += hs[(rg + 2 * r) * 128 + k] * w;
    }
#pragma unroll
    for (int r = 0; r < 8; r++)
        out[(block_row + rg + 2 * r) * 128 + col] = acc[r];
}

// fused Z (h@WqT) + P0 (h@Wih0+bih0); grid (400, 4)
__global__ void k_zp(const float* __restrict__ h, const float* __restrict__ WqT,
                     const float* __restrict__ Wih, const float* __restrict__ bih,
                     float* __restrict__ Z, float* __restrict__ P0) {
    __shared__ float hs[16 * 128];
    int block_row = blockIdx.x * 16;
    int tid = threadIdx.x;
    int c = tid & 127;
    int rg = tid >> 7;
    int y = blockIdx.y;
    for (int i = tid; i < 16 * 128; i += 256) hs[i] = h[block_row * 128 + i];
    __syncthreads();
    float acc[8] = {0.f, 0.f, 0.f, 0.f, 0.f, 0.f, 0.f, 0.f};
    if (y == 0) {
        for (int k = 0; k < 128; k++) {
            float w = WqT[k * 128 + c];
#pragma unroll
            for (int r = 0; r < 8; r++) acc[r] += hs[(rg + 2 * r) * 128 + k] * w;
        }
#pragma unroll
        for (int r = 0; r < 8; r++)
            Z[(block_row + rg + 2 * r) * 128 + c] = acc[r];
    } else {
        int col = (y - 1) * 128 + c;
        for (int k = 0; k < 128; k++) {
            float w = Wih[k * 384 + col];
#pragma unroll
            for (int r = 0; r < 8; r++) acc[r] += hs[(rg + 2 * r) * 128 + k] * w;
        }
        float bb = bih[col];
#pragma unroll
        for (int r = 0; r < 8; r++)
            P0[(size_t)(block_row + rg + 2 * r) * 384 + col] = acc[r] + bb;
    }
}

__global__ void k_transpose128(const float* __restrict__ Wq, float* __restrict__ WqT) {
    int i = blockIdx.x * 256 + threadIdx.x;
    if (i >= 128 * 128) return;
    int k = i >> 7, c = i & 127;
    WqT[k * 128 + c] = Wq[c * 128 + k];
}

// h' = relu(h@Ws + A@hw); 10 rows/block
__global__ void k_agg10(const float* __restrict__ h, const float* __restrict__ Ws,
                        const float* __restrict__ A, const float* __restrict__ hw,
                        float* __restrict__ out) {
    __shared__ float hs[10 * 128];
    __shared__ float As[10 * 100];
    int b = blockIdx.x / 10;
    int i0 = (blockIdx.x % 10) * 10;
    int tid = threadIdx.x;
    int col = tid & 127;
    int rg = tid >> 7;
    int rowbase = b * NN + i0;
    for (int i = tid; i < 10 * 128; i += 256) hs[i] = h[rowbase * 128 + i];
    for (int i = tid; i < 10 * 100; i += 256) As[i] = A[rowbase * 100 + i];
    __syncthreads();
    float acc[5] = {0.f, 0.f, 0.f, 0.f, 0.f};
    for (int k = 0; k < 128; k++) {
        float w = Ws[k * 128 + col];
#pragma unroll
        for (int r = 0; r < 5; r++) acc[r] += hs[(rg + 2 * r) * 128 + k] * w;
    }
    const float* hwb = hw + b * NN * 128;
    for (int j = 0; j < NN; j++) {
        float v = hwb[j * 128 + col];
#pragma unroll
        for (int r = 0; r < 5; r++) acc[r] += As[(rg + 2 * r) * 100 + j] * v;
    }
#pragma unroll
    for (int r = 0; r < 5; r++)
        out[(rowbase + rg + 2 * r) * 128 + col] = fmaxf(acc[r], 0.0f);
}

// fused predict + zero of solution matrix
__global__ void k_predict_zero(const float* __restrict__ dis, const float* __restrict__ We,
                               const float* __restrict__ be, const float* __restrict__ Wc,
                               const float* __restrict__ bc, float* __restrict__ out3,
                               float* __restrict__ zp) {
    int bid = blockIdx.x, tid = threadIdx.x;
    if (bid >= 1250) {
        int i = (bid - 1250) * 256 + tid;
        float4 z; z.x = 0.f; z.y = 0.f; z.z = 0.f; z.w = 0.f;
        ((float4*)zp)[i] = z;
        return;
    }
    __shared__ float sWe[128], sbe[128], sc0[128], sc1[128];
    if (tid < 128) {
        sWe[tid] = We[tid];
        sbe[tid] = be[tid];
        sc0[tid] = Wc[tid * 2];
        sc1[tid] = Wc[tid * 2 + 1];
    }
    __syncthreads();
    float b0 = bc[0], b1 = bc[1];
    int p0 = bid * 512 + tid, p1 = p0 + 256;
    float d0 = dis[p0], d1 = dis[p1];
    float a00 = b0, a01 = b1, a10 = b0, a11 = b1;
    for (int k = 0; k < 128; k++) {
        float we = sWe[k], bbe = sbe[k], c0 = sc0[k], c1 = sc1[k];
        float e0 = fmaxf(d0 * we + bbe, 0.0f);
        float e1 = fmaxf(d1 * we + bbe, 0.0f);
        a00 += e0 * c0; a01 += e0 * c1;
        a10 += e1 * c0; a11 += e1 * c1;
    }
    {
        float m = fmaxf(a00, a01);
        float q0 = expf(a00 - m), q1 = expf(a01 - m);
        float inv = 1.0f / (q0 + q1);
        out3[p0 * 2] = q0 * inv;
        out3[p0 * 2 + 1] = q1 * inv;
    }
    {
        float m = fmaxf(a10, a11);
        float q0 = expf(a10 - m), q1 = expf(a11 - m);
        float inv = 1.0f / (q0 + q1);
        out3[p1 * 2] = q0 * inv;
        out3[p1 * 2 + 1] = q1 * inv;
    }
}

// ---------------- shared matvec tile (spill-proof, ~40 VGPR) ----------------
__device__ __forceinline__ void matvec_tile4(const float* __restrict__ W,   // &W[k0*384 + j0]
                                             const float* __restrict__ hp,  // &h[k0]; modes +0,+132
                                             int nk4,
                                             float* __restrict__ pg0,
                                             float* __restrict__ pg1) {
    float a00 = 0.f, a01 = 0.f, a02 = 0.f, a03 = 0.f;
    float a10 = 0.f, a11 = 0.f, a12 = 0.f, a13 = 0.f;
#pragma unroll 4
    for (int k4 = 0; k4 < nk4; ++k4) {
        float4 hA = *(const float4*)(hp + 4 * k4);
        float4 hB = *(const float4*)(hp + 132 + 4 * k4);
        const float* Wk = W + (size_t)(4 * k4) * T3;
        float4 w0 = *(const float4*)(Wk);
        float4 w1 = *(const float4*)(Wk + T3);
        float4 w2 = *(const float4*)(Wk + 2 * T3);
        float4 w3 = *(const float4*)(Wk + 3 * T3);
        a00 += hA.x * w0.x; a01 += hA.x * w0.y; a02 += hA.x * w0.z; a03 += hA.x * w0.w;
        a10 += hB.x * w0.x; a11 += hB.x * w0.y; a12 += hB.x * w0.z; a13 += hB.x * w0.w;
        a00 += hA.y * w1.x; a01 += hA.y * w1.y; a02 += hA.y * w1.z; a03 += hA.y * w1.w;
        a10 += hB.y * w1.x; a11 += hB.y * w1.y; a12 += hB.y * w1.z; a13 += hB.y * w1.w;
        a00 += hA.z * w2.x; a01 += hA.z * w2.y; a02 += hA.z * w2.z; a03 += hA.z * w2.w;
        a10 += hB.z * w2.x; a11 += hB.z * w2.y; a12 += hB.z * w2.z; a13 += hB.z * w2.w;
        a00 += hA.w * w3.x; a01 += hA.w * w3.y; a02 += hA.w * w3.z; a03 += hA.w * w3.w;
        a10 += hB.w * w3.x; a11 += hB.w * w3.y; a12 += hB.w * w3.z; a13 += hB.w * w3.w;
    }
    float4 o;
    o.x = a00; o.y = a01; o.z = a02; o.w = a03;
    *(float4*)pg0 = o;
    o.x = a10; o.y = a11; o.z = a12; o.w = a13;
    *(float4*)pg1 = o;
}

// ---------------- decoder v9: 768 threads, ALL 12 waves stream weights ----------------
// Tests the outstanding-load-starvation hypothesis: decode4 streams with only 6 of 8
// waves (31.5 B/cyc/CU); 12 streaming waves double in-flight bytes. Aux work moved:
// gi0 prefetch -> registers at loop top (in flight during phase A); RNG/gumbel ->
// threads 256..355 during phase B.
__global__ __launch_bounds__(768, 3) void k_decode9(
    const float* __restrict__ P0,       // [6400, 384]  x@Wih0 + bih0
    const float* __restrict__ Z,        // [6400, 128]  x@Wq^T
    const float* __restrict__ dis,
    const float* __restrict__ Wih,      // [2,128,384]
    const float* __restrict__ Whh,      // [2,128,384]
    const float* __restrict__ bih,
    const float* __restrict__ bhh,
    float* __restrict__ out) {
    __shared__ float Zs[NN * 132];          // 52.8 KB
    __shared__ float h0s[2 * 132], h1s[2 * 132];
    __shared__ float pgA[4 * 2 * 392];      // gh0 partials [ks4][m][392]
    __shared__ float pgB[4 * 2 * 392];      // gh1 partials
    __shared__ float pgC[8 * 2 * 392];      // gi1 partials [ks8][m][392]
    __shared__ float sbhh0[T3], sbih1[T3], sbhh1[T3];
    __shared__ float pl[2 * 2 * 100];       // [m][ks][n]
    __shared__ float gum[128];
    __shared__ int s_ind2[2];

    const int tid = threadIdx.x;
    const int b = blockIdx.x;

    const float* __restrict__ Wih1 = Wih + 128 * T3;

    // ---- static staging ----
    for (int i4 = tid; i4 < NN * 32; i4 += 768) {
        int r = i4 >> 5, c4 = (i4 & 31) * 4;
        *(float4*)&Zs[r * 132 + c4] = *(const float4*)&Z[(b * NN + r) * 128 + c4];
    }
    if (tid < T3) {
        sbhh0[tid] = bhh[tid];
        sbih1[tid] = bih[T3 + tid];
        sbhh1[tid] = bhh[T3 + tid];
    }
    if (tid < 256) {
        int m = tid >> 7, i = tid & 127;
        h0s[m * 132 + i] = 0.0f;
        h1s[m * 132 + i] = 0.0f;
    }
    if (tid == 0) { s_ind2[0] = 0; s_ind2[1] = 0; }

    unsigned kk0, kk1;
    tf2x32(0u, 42u, 0u, 0u, kk0, kk1);   // k1 of split(key(42)); advanced uniformly below

    // phase-A matvec role (all 768 threads)
    const int unitA = tid / 384;             // 0: Whh0*h0 -> pgA, 1: Whh1*h1 -> pgB
    const int rA = tid - unitA * 384;
    const int ksA = rA / 96, j4A = rA - ksA * 96;
    const int j0A = j4A * 4, k0A = ksA * 32;
    // phase-C matvec role
    const int ksC = tid / 96, j4C = tid - ksC * 96;
    const int j0C = j4C * 4, k0C = ksC * 16;

    int lastm = 0;       // tracked by tid<128 (selection threads)
    float dist = 0.0f;
    __syncthreads();

    for (int t = 0; t < NN - 1; t++) {
        // ---- RNG chain advance (uniform in all threads) ----
        unsigned sk0, sk1, nkA, nkB;
        tf2x32(kk0, kk1, 0u, 1u, sk0, sk1);
        tf2x32(kk0, kk1, 0u, 0u, nkA, nkB);
        kk0 = nkA; kk1 = nkB;

        // ---- gi0 prefetch into registers (loads in flight during phase A) ----
        float pf_r = 0.f, pf_z = 0.f, pf_n = 0.f;
        if (tid < 256) {
            const float* P0row = P0 + (size_t)(b * NN + s_ind2[tid >> 7]) * T3;
            int i = tid & 127;
            pf_r = P0row[i];
            pf_z = P0row[i + 128];
            pf_n = P0row[i + 256];
        }

        // ===== phase A: gh0 & gh1 partials — ALL 768 threads stream =====
        {
            const float* W = Whh + unitA * (128 * T3) + (size_t)k0A * T3 + j0A;
            const float* hp = ((unitA == 0) ? h0s : h1s) + k0A;
            float* pg = (unitA == 0) ? pgA : pgB;
            matvec_tile4(W, hp, 8,
                         &pg[(ksA * 2 + 0) * 392 + j0A],
                         &pg[(ksA * 2 + 1) * 392 + j0A]);
        }
        __syncthreads();

        // ===== phase B: h0 update (256 thr) + gumbel (thr 256..355) =====
        if (tid < 256) {
            int m = tid >> 7, i = tid & 127;
            float ghr = sbhh0[i], ghz = sbhh0[i + 128], ghn = sbhh0[i + 256];
#pragma unroll
            for (int ks = 0; ks < 4; ks++) {
                int pb = (ks * 2 + m) * 392;
                ghr += pgA[pb + i];
                ghz += pgA[pb + i + 128];
                ghn += pgA[pb + i + 256];
            }
            float rr = 1.0f / (1.0f + expf(-(pf_r + ghr)));
            float zz = 1.0f / (1.0f + expf(-(pf_z + ghz)));
            float nn = tanhf(pf_n + rr * ghn);
            h0s[m * 132 + i] = (1.0f - zz) * nn + zz * h0s[m * 132 + i];
        } else if (tid < 356) {
            int u = tid - 256;
            gum[u] = gumbel_f(sk0, sk1, (unsigned)(b * NN + u));
        }
        __syncthreads();

        // ===== phase C: gi1 partials — ALL 768 threads stream =====
        {
            const float* W = Wih1 + (size_t)k0C * T3 + j0C;
            matvec_tile4(W, h0s + k0C, 4,
                         &pgC[(ksC * 2 + 0) * 392 + j0C],
                         &pgC[(ksC * 2 + 1) * 392 + j0C]);
        }
        __syncthreads();

        // ===== phase D: h1 update (256 thr) =====
        if (tid < 256) {
            int m = tid >> 7, i = tid & 127;
            float gir = sbih1[i], giz = sbih1[i + 128], gin = sbih1[i + 256];
#pragma unroll
            for (int ks = 0; ks < 8; ks++) {
                int pb = (ks * 2 + m) * 392;
                gir += pgC[pb + i];
                giz += pgC[pb + i + 128];
                gin += pgC[pb + i + 256];
            }
            float ghr = sbhh1[i], ghz = sbhh1[i + 128], ghn = sbhh1[i + 256];
#pragma unroll
            for (int ks = 0; ks < 4; ks++) {
                int pb = (ks * 2 + m) * 392;
                ghr += pgB[pb + i];
                ghz += pgB[pb + i + 128];
                ghn += pgB[pb + i + 256];
            }
            float rr = 1.0f / (1.0f + expf(-(gir + ghr)));
            float zz = 1.0f / (1.0f + expf(-(giz + ghz)));
            float nn = tanhf(gin + rr * ghn);
            h1s[m * 132 + i] = (1.0f - zz) * nn + zz * h1s[m * 132 + i];
        }
        __syncthreads();

        // ===== phase E: logits partials (200 thr) =====
        if (tid < 200) {
            int ks = tid / 100, n = tid - ks * 100;
            int kk0p = ks * 64;
            const float* Zp = &Zs[n * 132 + kk0p];
            const float* hp = &h1s[kk0p];
            float a0 = 0.f, a1 = 0.f;
#pragma unroll 4
            for (int q = 0; q < 16; q++) {
                float4 z4 = *(const float4*)(Zp + 4 * q);
                float4 hA = *(const float4*)(hp + 4 * q);
                float4 hB = *(const float4*)(hp + 132 + 4 * q);
                a0 += hA.x * z4.x; a0 += hA.y * z4.y; a0 += hA.z * z4.z; a0 += hA.w * z4.w;
                a1 += hB.x * z4.x; a1 += hB.y * z4.y; a1 += hB.z * z4.z; a1 += hB.w * z4.w;
            }
            pl[(0 * 2 + ks) * 100 + n] = a0;
            pl[(1 * 2 + ks) * 100 + n] = a1;
        }
        __syncthreads();

        // ===== phase F: softmax stats + selection (wave0: sample, wave1: greedy) =====
        if (tid < 128) {
            const int m = tid >> 6, lane = tid & 63;
            float v0, v1 = -__builtin_inff();
            v0 = (pl[(m * 2 + 0) * 100 + lane] + pl[(m * 2 + 1) * 100 + lane]) * SCALEF;
            if (lane + 64 < NN)
                v1 = (pl[(m * 2 + 0) * 100 + lane + 64] + pl[(m * 2 + 1) * 100 + lane + 64]) * SCALEF;
            float mx = fmaxf(v0, v1);
            for (int off = 32; off > 0; off >>= 1) mx = fmaxf(mx, __shfl_xor(mx, off));
            float e = expf(v0 - mx) + ((lane + 64 < NN) ? expf(v1 - mx) : 0.0f);
            for (int off = 32; off > 0; off >>= 1) e += __shfl_xor(e, off);
            float a0 = v0, a1 = v1;
            if (m == 0) {
                a0 += gum[lane];
                if (lane + 64 < NN) a1 += gum[lane + 64];
            }
            float bv; int bi;
            if (a1 > a0) { bv = a1; bi = lane + 64; } else { bv = a0; bi = lane; }
            for (int off = 32; off > 0; off >>= 1) {
                float ov = __shfl_xor(bv, off);
                int   oi = __shfl_xor(bi, off);
                if (ov > bv || (ov == bv && oi < bi)) { bv = ov; bi = oi; }
            }
            int ind = bi;
            float la = __shfl(v0, ind & 63);
            float lb = __shfl(v1, ind & 63);
            float lv = (ind < 64) ? la : lb;
            if (lane == 0) {
                if (m == 0) out[O0 + b * (NN - 1) + t] = lv - mx - logf(e);
                else        out[O4 + (size_t)b * NN * NN + lastm * NN + ind] = 1.0f;
                s_ind2[m] = ind;
            }
            dist += dis[b * NN * NN + lastm * NN + ind];
            lastm = ind;
        }
        __syncthreads();
    }

    if (tid == 0)  out[O1 + b] = dist;
    if (tid == 64) out[O2 + b] = dist;
}

// ---------------- host launcher ----------------
extern "C" void kernel_launch(void* const* d_in, const int* in_sizes, int n_in,
                              void* d_out, int out_size, void* d_ws, size_t ws_size,
                              hipStream_t stream) {
    (void)in_sizes; (void)n_in; (void)out_size; (void)ws_size;
    const float* node   = (const float*)d_in[0];
    const float* demand = (const float*)d_in[1];
    const float* dis    = (const float*)d_in[2];
    const float* Wn0    = (const float*)d_in[3];
    const float* bn0    = (const float*)d_in[4];
    const float* Ws     = (const float*)d_in[5];
    const float* Wngh   = (const float*)d_in[6];
    const float* We     = (const float*)d_in[7];
    const float* be     = (const float*)d_in[8];
    const float* Wih    = (const float*)d_in[9];
    const float* Whh    = (const float*)d_in[10];
    const float* bih    = (const float*)d_in[11];
    const float* bhh    = (const float*)d_in[12];
    const float* Wq     = (const float*)d_in[13];
    const float* Wc     = (const float*)d_in[14];
    const float* bc     = (const float*)d_in[15];
    float* out = (float*)d_out;
    float* ws  = (float*)d_ws;

    float* hA  = ws;                // 819200
    float* hB  = ws + 819200;       // 819200
    float* hw  = ws + 1638400;      // hw during encoder; Z after
    float* A   = ws + 2457600;      // A during encoder
    float* P0  = ws + 2457600;      // P0 overlays A after encoder
    float* WqT = ws + 4915200;      // 16384

    hipLaunchKernelGGL(k_predict_zero, dim3(1875), dim3(256), 0, stream,
                       dis, We, be, Wc, bc, out + O3, out + O4);

    hipLaunchKernelGGL(k_embed_adj, dim3(4800), dim3(256), 0, stream,
                       node, demand, Wn0, bn0, dis, hA, A);

    float* cur = hA;
    float* nxt = hB;
    for (int l = 0; l < 3; l++) {
        hipLaunchKernelGGL(k_hw16, dim3(400), dim3(256), 0, stream, cur, Wngh + l * 16384, hw);
        hipLaunchKernelGGL(k_agg10, dim3(640), dim3(256), 0, stream, cur, Ws + l * 16384, A, hw, nxt);
        float* tswap = cur; cur = nxt; nxt = tswap;
    }
    // cur == hB holds the final encoder output

    hipLaunchKernelGGL(k_transpose128, dim3(64), dim3(256), 0, stream, Wq, WqT);
    hipLaunchKernelGGL(k_zp, dim3(400, 4), dim3(256), 0, stream, cur, WqT, Wih, bih, hw, P0);

    hipLaunchKernelGGL(k_decode9, dim3(64), dim3(768), 0, stream,
                       P0, hw, dis, Wih, Whh, bih, bhh, out);
}

// Round 11
// 911.004 us; speedup vs baseline: 2.2736x; 1.0136x over previous
//
#include <hip/hip_runtime.h>
#include <math.h>

// Problem constants
#define BB 64
#define NN 100
#define HH 128
#define T3 384

// Output layout (floats, concatenated in return order)
#define O0 0            // sample_logprob [64,99]
#define O1 6336         // sample_distance [64,1]
#define O2 6400         // greedy_distance [64,1]
#define O3 6464         // predict_matrix [64,100,100,2]
#define O4 1286464      // greedy_solution_matrix [64,100,100]

#define TINYF 1.17549435e-38f
#define SCALEF 0.08838834764831845f

// ---------------- threefry2x32 (exact JAX implementation) ----------------
__device__ __forceinline__ unsigned rotl32(unsigned x, int d) {
    return (x << d) | (x >> (32 - d));
}

__device__ __forceinline__ void tf2x32(unsigned ks0, unsigned ks1,
                                       unsigned x0, unsigned x1,
                                       unsigned& o0, unsigned& o1) {
    unsigned ks2 = ks0 ^ ks1 ^ 0x1BD11BDAu;
    x0 += ks0; x1 += ks1;
    x0 += x1; x1 = rotl32(x1, 13); x1 ^= x0;
    x0 += x1; x1 = rotl32(x1, 15); x1 ^= x0;
    x0 += x1; x1 = rotl32(x1, 26); x1 ^= x0;
    x0 += x1; x1 = rotl32(x1, 6);  x1 ^= x0;
    x0 += ks1; x1 += ks2 + 1u;
    x0 += x1; x1 = rotl32(x1, 17); x1 ^= x0;
    x0 += x1; x1 = rotl32(x1, 29); x1 ^= x0;
    x0 += x1; x1 = rotl32(x1, 16); x1 ^= x0;
    x0 += x1; x1 = rotl32(x1, 24); x1 ^= x0;
    x0 += ks2; x1 += ks0 + 2u;
    x0 += x1; x1 = rotl32(x1, 13); x1 ^= x0;
    x0 += x1; x1 = rotl32(x1, 15); x1 ^= x0;
    x0 += x1; x1 = rotl32(x1, 26); x1 ^= x0;
    x0 += x1; x1 = rotl32(x1, 6);  x1 ^= x0;
    x0 += ks0; x1 += ks1 + 3u;
    x0 += x1; x1 = rotl32(x1, 17); x1 ^= x0;
    x0 += x1; x1 = rotl32(x1, 29); x1 ^= x0;
    x0 += x1; x1 = rotl32(x1, 16); x1 ^= x0;
    x0 += x1; x1 = rotl32(x1, 24); x1 ^= x0;
    x0 += ks1; x1 += ks2 + 4u;
    x0 += x1; x1 = rotl32(x1, 13); x1 ^= x0;
    x0 += x1; x1 = rotl32(x1, 15); x1 ^= x0;
    x0 += x1; x1 = rotl32(x1, 26); x1 ^= x0;
    x0 += x1; x1 = rotl32(x1, 6);  x1 ^= x0;
    x0 += ks2; x1 += ks0 + 5u;
    o0 = x0; o1 = x1;
}

__device__ __forceinline__ float gumbel_f(unsigned k0, unsigned k1, unsigned f) {
    unsigned o0, o1;
    tf2x32(k0, k1, 0u, f, o0, o1);
    unsigned bits = o0 ^ o1;
    float u01 = __uint_as_float((bits >> 9) | 0x3F800000u) - 1.0f;
    float u = fmaxf(TINYF, u01 * (1.0f - TINYF) + TINYF);
    return -logf(-logf(u));
}

// ---------------- fused pre-kernel: embed + adj + transpose + predict + zero ----------
// blocks [0,3200): embed; [3200,4800): adj (4 rows, 1 wave each); [4800,4864): Wq
// transpose; [4864,6114): predict (2 pos/thread, float4 inner); [6114,6739): zero.
__global__ void k_pre0(const float* __restrict__ node, const float* __restrict__ demand,
                       const float* __restrict__ Wn0, const float* __restrict__ bn0,
                       const float* __restrict__ dis,
                       const float* __restrict__ We, const float* __restrict__ be,
                       const float* __restrict__ Wc, const float* __restrict__ bc,
                       const float* __restrict__ Wq,
                       float* __restrict__ h, float* __restrict__ A,
                       float* __restrict__ WqT,
                       float* __restrict__ out3, float* __restrict__ zp) {
    __shared__ float sWe[128], sbe[128], sc0[128], sc1[128];
    int bid = blockIdx.x, tid = threadIdx.x;
    if (bid < 3200) {
        int idx = bid * 256 + tid;
        int r = idx >> 7, c = idx & 127;
        float v = node[r * 2] * Wn0[c] + node[r * 2 + 1] * Wn0[128 + c]
                + demand[r] * Wn0[256 + c] + bn0[c];
        h[idx] = fmaxf(v, 0.0f);
    } else if (bid < 4800) {
        int row = (bid - 3200) * 4 + (tid >> 6);
        int l = tid & 63;
        const float* d = dis + row * NN;
        float v0 = -d[l];
        float v1 = (l + 64 < NN) ? -d[l + 64] : -__builtin_inff();
        float m = fmaxf(v0, v1);
        for (int off = 32; off > 0; off >>= 1) m = fmaxf(m, __shfl_xor(m, off));
        float e0 = expf(v0 - m);
        float e1 = (l + 64 < NN) ? expf(v1 - m) : 0.0f;
        float s = e0 + e1;
        for (int off = 32; off > 0; off >>= 1) s += __shfl_xor(s, off);
        float inv = 1.0f / s;
        A[row * NN + l] = e0 * inv;
        if (l + 64 < NN) A[row * NN + l + 64] = e1 * inv;
    } else if (bid < 4864) {
        int i = (bid - 4800) * 256 + tid;
        int k = i >> 7, c = i & 127;
        WqT[k * 128 + c] = Wq[c * 128 + k];
    } else if (bid < 6114) {
        if (tid < 128) {
            sWe[tid] = We[tid];
            sbe[tid] = be[tid];
            sc0[tid] = Wc[tid * 2];
            sc1[tid] = Wc[tid * 2 + 1];
        }
        __syncthreads();
        float b0 = bc[0], b1 = bc[1];
        int p0 = (bid - 4864) * 512 + tid, p1 = p0 + 256;
        float d0 = dis[p0], d1 = dis[p1];
        float a00 = b0, a01 = b1, a10 = b0, a11 = b1;
        for (int k4 = 0; k4 < 32; k4++) {
            float4 we = *(const float4*)&sWe[4 * k4];
            float4 bb = *(const float4*)&sbe[4 * k4];
            float4 c0 = *(const float4*)&sc0[4 * k4];
            float4 c1 = *(const float4*)&sc1[4 * k4];
            float e0, e1;
            e0 = fmaxf(d0 * we.x + bb.x, 0.0f); a00 += e0 * c0.x; a01 += e0 * c1.x;
            e1 = fmaxf(d1 * we.x + bb.x, 0.0f); a10 += e1 * c0.x; a11 += e1 * c1.x;
            e0 = fmaxf(d0 * we.y + bb.y, 0.0f); a00 += e0 * c0.y; a01 += e0 * c1.y;
            e1 = fmaxf(d1 * we.y + bb.y, 0.0f); a10 += e1 * c0.y; a11 += e1 * c1.y;
            e0 = fmaxf(d0 * we.z + bb.z, 0.0f); a00 += e0 * c0.z; a01 += e0 * c1.z;
            e1 = fmaxf(d1 * we.z + bb.z, 0.0f); a10 += e1 * c0.z; a11 += e1 * c1.z;
            e0 = fmaxf(d0 * we.w + bb.w, 0.0f); a00 += e0 * c0.w; a01 += e0 * c1.w;
            e1 = fmaxf(d1 * we.w + bb.w, 0.0f); a10 += e1 * c0.w; a11 += e1 * c1.w;
        }
        {
            float m = fmaxf(a00, a01);
            float q0 = expf(a00 - m), q1 = expf(a01 - m);
            float inv = 1.0f / (q0 + q1);
            out3[p0 * 2] = q0 * inv;
            out3[p0 * 2 + 1] = q1 * inv;
        }
        {
            float m = fmaxf(a10, a11);
            float q0 = expf(a10 - m), q1 = expf(a11 - m);
            float inv = 1.0f / (q0 + q1);
            out3[p1 * 2] = q0 * inv;
            out3[p1 * 2 + 1] = q1 * inv;
        }
    } else {
        int i = (bid - 6114) * 256 + tid;
        float4 z; z.x = 0.f; z.y = 0.f; z.z = 0.f; z.w = 0.f;
        ((float4*)zp)[i] = z;
    }
}

// out[6400x128] = h @ W[128x128]; 16 rows/block; float4 h reads, ordered FMAs
__global__ void k_hw16(const float* __restrict__ h, const float* __restrict__ W,
                       float* __restrict__ out) {
    __shared__ float hs[16 * 128];
    int block_row = blockIdx.x * 16;
    int tid = threadIdx.x;
    int col = tid & 127;
    int rg = tid >> 7;
    for (int i = tid; i < 16 * 32; i += 256)
        ((float4*)hs)[i] = ((const float4*)(h + block_row * 128))[i];
    __syncthreads();
    float acc[8] = {0.f, 0.f, 0.f, 0.f, 0.f, 0.f, 0.f, 0.f};
    for (int k4 = 0; k4 < 32; k4++) {
        int k = 4 * k4;
        float w0 = W[k * 128 + col], w1 = W[(k + 1) * 128 + col];
        float w2 = W[(k + 2) * 128 + col], w3 = W[(k + 3) * 128 + col];
#pragma unroll
        for (int r = 0; r < 8; r++) {
            float4 h4 = *(const float4*)&hs[(rg + 2 * r) * 128 + k];
            acc[r] += h4.x * w0; acc[r] += h4.y * w1;
            acc[r] += h4.z * w2; acc[r] += h4.w * w3;
        }
    }
#pragma unroll
    for (int r = 0; r < 8; r++)
        out[(block_row + rg + 2 * r) * 128 + col] = acc[r];
}

// fused Z (h@WqT) + P0 (h@Wih0+bih0); grid (400, 4); float4 h reads
__global__ void k_zp(const float* __restrict__ h, const float* __restrict__ WqT,
                     const float* __restrict__ Wih, const float* __restrict__ bih,
                     float* __restrict__ Z, float* __restrict__ P0) {
    __shared__ float hs[16 * 128];
    int block_row = blockIdx.x * 16;
    int tid = threadIdx.x;
    int c = tid & 127;
    int rg = tid >> 7;
    int y = blockIdx.y;
    for (int i = tid; i < 16 * 32; i += 256)
        ((float4*)hs)[i] = ((const float4*)(h + block_row * 128))[i];
    __syncthreads();
    float acc[8] = {0.f, 0.f, 0.f, 0.f, 0.f, 0.f, 0.f, 0.f};
    if (y == 0) {
        for (int k4 = 0; k4 < 32; k4++) {
            int k = 4 * k4;
            float w0 = WqT[k * 128 + c], w1 = WqT[(k + 1) * 128 + c];
            float w2 = WqT[(k + 2) * 128 + c], w3 = WqT[(k + 3) * 128 + c];
#pragma unroll
            for (int r = 0; r < 8; r++) {
                float4 h4 = *(const float4*)&hs[(rg + 2 * r) * 128 + k];
                acc[r] += h4.x * w0; acc[r] += h4.y * w1;
                acc[r] += h4.z * w2; acc[r] += h4.w * w3;
            }
        }
#pragma unroll
        for (int r = 0; r < 8; r++)
            Z[(block_row + rg + 2 * r) * 128 + c] = acc[r];
    } else {
        int col = (y - 1) * 128 + c;
        for (int k4 = 0; k4 < 32; k4++) {
            int k = 4 * k4;
            float w0 = Wih[k * 384 + col], w1 = Wih[(k + 1) * 384 + col];
            float w2 = Wih[(k + 2) * 384 + col], w3 = Wih[(k + 3) * 384 + col];
#pragma unroll
            for (int r = 0; r < 8; r++) {
                float4 h4 = *(const float4*)&hs[(rg + 2 * r) * 128 + k];
                acc[r] += h4.x * w0; acc[r] += h4.y * w1;
                acc[r] += h4.z * w2; acc[r] += h4.w * w3;
            }
        }
        float bb = bih[col];
#pragma unroll
        for (int r = 0; r < 8; r++)
            P0[(size_t)(block_row + rg + 2 * r) * 384 + col] = acc[r] + bb;
    }
}

// h' = relu(h@Ws + A@hw); 10 rows/block; float4 hs/As reads, ordered FMAs
__global__ void k_agg10(const float* __restrict__ h, const float* __restrict__ Ws,
                        const float* __restrict__ A, const float* __restrict__ hw,
                        float* __restrict__ out) {
    __shared__ float hs[10 * 128];
    __shared__ float As[10 * 100];
    int b = blockIdx.x / 10;
    int i0 = (blockIdx.x % 10) * 10;
    int tid = threadIdx.x;
    int col = tid & 127;
    int rg = tid >> 7;
    int rowbase = b * NN + i0;
    for (int i = tid; i < 10 * 32; i += 256)
        ((float4*)hs)[i] = ((const float4*)(h + rowbase * 128))[i];
    for (int i = tid; i < 10 * 25; i += 256)
        ((float4*)As)[i] = ((const float4*)(A + rowbase * 100))[i];
    __syncthreads();
    float acc[5] = {0.f, 0.f, 0.f, 0.f, 0.f};
    for (int k4 = 0; k4 < 32; k4++) {
        int k = 4 * k4;
        float w0 = Ws[k * 128 + col], w1 = Ws[(k + 1) * 128 + col];
        float w2 = Ws[(k + 2) * 128 + col], w3 = Ws[(k + 3) * 128 + col];
#pragma unroll
        for (int r = 0; r < 5; r++) {
            float4 h4 = *(const float4*)&hs[(rg + 2 * r) * 128 + k];
            acc[r] += h4.x * w0; acc[r] += h4.y * w1;
            acc[r] += h4.z * w2; acc[r] += h4.w * w3;
        }
    }
    const float* hwb = hw + b * NN * 128;
    for (int j4 = 0; j4 < 25; j4++) {
        int j = 4 * j4;
        float v0 = hwb[j * 128 + col], v1 = hwb[(j + 1) * 128 + col];
        float v2 = hwb[(j + 2) * 128 + col], v3 = hwb[(j + 3) * 128 + col];
#pragma unroll
        for (int r = 0; r < 5; r++) {
            float4 a4 = *(const float4*)&As[(rg + 2 * r) * 100 + j];
            acc[r] += a4.x * v0; acc[r] += a4.y * v1;
            acc[r] += a4.z * v2; acc[r] += a4.w * v3;
        }
    }
#pragma unroll
    for (int r = 0; r < 5; r++)
        out[(rowbase + rg + 2 * r) * 128 + col] = fmaxf(acc[r], 0.0f);
}

// ---------------- shared matvec tile (spill-proof, ~40 VGPR) ----------------
__device__ __forceinline__ void matvec_tile4(const float* __restrict__ W,   // &W[k0*384 + j0]
                                             const float* __restrict__ hp,  // &h[k0]; modes +0,+132
                                             int nk4,
                                             float* __restrict__ pg0,
                                             float* __restrict__ pg1) {
    float a00 = 0.f, a01 = 0.f, a02 = 0.f, a03 = 0.f;
    float a10 = 0.f, a11 = 0.f, a12 = 0.f, a13 = 0.f;
#pragma unroll 4
    for (int k4 = 0; k4 < nk4; ++k4) {
        float4 hA = *(const float4*)(hp + 4 * k4);
        float4 hB = *(const float4*)(hp + 132 + 4 * k4);
        const float* Wk = W + (size_t)(4 * k4) * T3;
        float4 w0 = *(const float4*)(Wk);
        float4 w1 = *(const float4*)(Wk + T3);
        float4 w2 = *(const float4*)(Wk + 2 * T3);
        float4 w3 = *(const float4*)(Wk + 3 * T3);
        a00 += hA.x * w0.x; a01 += hA.x * w0.y; a02 += hA.x * w0.z; a03 += hA.x * w0.w;
        a10 += hB.x * w0.x; a11 += hB.x * w0.y; a12 += hB.x * w0.z; a13 += hB.x * w0.w;
        a00 += hA.y * w1.x; a01 += hA.y * w1.y; a02 += hA.y * w1.z; a03 += hA.y * w1.w;
        a10 += hB.y * w1.x; a11 += hB.y * w1.y; a12 += hB.y * w1.z; a13 += hB.y * w1.w;
        a00 += hA.z * w2.x; a01 += hA.z * w2.y; a02 += hA.z * w2.z; a03 += hA.z * w2.w;
        a10 += hB.z * w2.x; a11 += hB.z * w2.y; a12 += hB.z * w2.z; a13 += hB.z * w2.w;
        a00 += hA.w * w3.x; a01 += hA.w * w3.y; a02 += hA.w * w3.z; a03 += hA.w * w3.w;
        a10 += hB.w * w3.x; a11 += hB.w * w3.y; a12 += hB.w * w3.z; a13 += hB.w * w3.w;
    }
    float4 o;
    o.x = a00; o.y = a01; o.z = a02; o.w = a03;
    *(float4*)pg0 = o;
    o.x = a10; o.y = a11; o.z = a12; o.w = a13;
    *(float4*)pg1 = o;
}

// ---------------- decoder v10: decode9 + register-resident Wih1 tile ----------------
// The Wih1 tile each thread needs in phase C is STEP-INVARIANT: 16 float4 = 64 VGPRs,
// loaded once before the loop. Eliminates 192 KB/step (33%) of the L2 stream that
// decode9 showed to be the exact step-time determinant (590 KB / 33.8 B/cyc).
// Budget: decode9 used 84 VGPR; +64 = ~150 < 168 cap (768 thr = 3 waves/EU).
// Spill sentinel: WRITE_SIZE must stay ~37 KB.
__global__ __launch_bounds__(768, 3) void k_decode10(
    const float* __restrict__ P0,       // [6400, 384]  x@Wih0 + bih0
    const float* __restrict__ Z,        // [6400, 128]  x@Wq^T
    const float* __restrict__ dis,
    const float* __restrict__ Wih,      // [2,128,384]
    const float* __restrict__ Whh,      // [2,128,384]
    const float* __restrict__ bih,
    const float* __restrict__ bhh,
    float* __restrict__ out) {
    __shared__ float Zs[NN * 132];          // 52.8 KB
    __shared__ float h0s[2 * 132], h1s[2 * 132];
    __shared__ float pgA[4 * 2 * 392];      // gh0 partials [ks4][m][392]
    __shared__ float pgB[4 * 2 * 392];      // gh1 partials
    __shared__ float pgC[8 * 2 * 392];      // gi1 partials [ks8][m][392]
    __shared__ float sbhh0[T3], sbih1[T3], sbhh1[T3];
    __shared__ float pl[2 * 2 * 100];       // [m][ks][n]
    __shared__ float gum[128];
    __shared__ int s_ind2[2];

    const int tid = threadIdx.x;
    const int b = blockIdx.x;

    const float* __restrict__ Wih1 = Wih + 128 * T3;

    // phase-A matvec role (all 768 threads)
    const int unitA = tid / 384;             // 0: Whh0*h0 -> pgA, 1: Whh1*h1 -> pgB
    const int rA = tid - unitA * 384;
    const int ksA = rA / 96, j4A = rA - ksA * 96;
    const int j0A = j4A * 4, k0A = ksA * 32;
    // phase-C matvec role
    const int ksC = tid / 96, j4C = tid - ksC * 96;
    const int j0C = j4C * 4, k0C = ksC * 16;

    // ---- load step-invariant Wih1 tile into registers (16 float4 = 64 VGPR) ----
    float4 pw[16];
    {
        const float* Wc = Wih1 + (size_t)k0C * T3 + j0C;
#pragma unroll
        for (int k = 0; k < 16; k++)
            pw[k] = *(const float4*)(Wc + (size_t)k * T3);
    }

    // ---- static staging ----
    for (int i4 = tid; i4 < NN * 32; i4 += 768) {
        int r = i4 >> 5, c4 = (i4 & 31) * 4;
        *(float4*)&Zs[r * 132 + c4] = *(const float4*)&Z[(b * NN + r) * 128 + c4];
    }
    if (tid < T3) {
        sbhh0[tid] = bhh[tid];
        sbih1[tid] = bih[T3 + tid];
        sbhh1[tid] = bhh[T3 + tid];
    }
    if (tid < 256) {
        int m = tid >> 7, i = tid & 127;
        h0s[m * 132 + i] = 0.0f;
        h1s[m * 132 + i] = 0.0f;
    }
    if (tid == 0) { s_ind2[0] = 0; s_ind2[1] = 0; }

    unsigned kk0, kk1;
    tf2x32(0u, 42u, 0u, 0u, kk0, kk1);   // k1 of split(key(42)); advanced uniformly below

    int lastm = 0;       // tracked by tid<128 (selection threads)
    float dist = 0.0f;
    __syncthreads();

    for (int t = 0; t < NN - 1; t++) {
        // ---- RNG chain advance (uniform in all threads) ----
        unsigned sk0, sk1, nkA, nkB;
        tf2x32(kk0, kk1, 0u, 1u, sk0, sk1);
        tf2x32(kk0, kk1, 0u, 0u, nkA, nkB);
        kk0 = nkA; kk1 = nkB;

        // ---- gi0 prefetch into registers (loads in flight during phase A) ----
        float pf_r = 0.f, pf_z = 0.f, pf_n = 0.f;
        if (tid < 256) {
            const float* P0row = P0 + (size_t)(b * NN + s_ind2[tid >> 7]) * T3;
            int i = tid & 127;
            pf_r = P0row[i];
            pf_z = P0row[i + 128];
            pf_n = P0row[i + 256];
        }

        // ===== phase A: gh0 & gh1 partials — all 768 threads stream Whh =====
        {
            const float* W = Whh + unitA * (128 * T3) + (size_t)k0A * T3 + j0A;
            const float* hp = ((unitA == 0) ? h0s : h1s) + k0A;
            float* pg = (unitA == 0) ? pgA : pgB;
            matvec_tile4(W, hp, 8,
                         &pg[(ksA * 2 + 0) * 392 + j0A],
                         &pg[(ksA * 2 + 1) * 392 + j0A]);
        }
        __syncthreads();

        // ===== phase B: h0 update (256 thr) + gumbel (thr 256..355) =====
        if (tid < 256) {
            int m = tid >> 7, i = tid & 127;
            float ghr = sbhh0[i], ghz = sbhh0[i + 128], ghn = sbhh0[i + 256];
#pragma unroll
            for (int ks = 0; ks < 4; ks++) {
                int pb = (ks * 2 + m) * 392;
                ghr += pgA[pb + i];
                ghz += pgA[pb + i + 128];
                ghn += pgA[pb + i + 256];
            }
            float rr = 1.0f / (1.0f + expf(-(pf_r + ghr)));
            float zz = 1.0f / (1.0f + expf(-(pf_z + ghz)));
            float nn = tanhf(pf_n + rr * ghn);
            h0s[m * 132 + i] = (1.0f - zz) * nn + zz * h0s[m * 132 + i];
        } else if (tid < 356) {
            int u = tid - 256;
            gum[u] = gumbel_f(sk0, sk1, (unsigned)(b * NN + u));
        }
        __syncthreads();

        // ===== phase C: gi1 partials — weights from registers, ZERO loads =====
        {
            const float* hp = h0s + k0C;
            float a00 = 0.f, a01 = 0.f, a02 = 0.f, a03 = 0.f;
            float a10 = 0.f, a11 = 0.f, a12 = 0.f, a13 = 0.f;
#pragma unroll
            for (int k4 = 0; k4 < 4; ++k4) {
                float4 hA = *(const float4*)(hp + 4 * k4);
                float4 hB = *(const float4*)(hp + 132 + 4 * k4);
                float4 w0 = pw[4 * k4 + 0];
                float4 w1 = pw[4 * k4 + 1];
                float4 w2 = pw[4 * k4 + 2];
                float4 w3 = pw[4 * k4 + 3];
                a00 += hA.x * w0.x; a01 += hA.x * w0.y; a02 += hA.x * w0.z; a03 += hA.x * w0.w;
                a10 += hB.x * w0.x; a11 += hB.x * w0.y; a12 += hB.x * w0.z; a13 += hB.x * w0.w;
                a00 += hA.y * w1.x; a01 += hA.y * w1.y; a02 += hA.y * w1.z; a03 += hA.y * w1.w;
                a10 += hB.y * w1.x; a11 += hB.y * w1.y; a12 += hB.y * w1.z; a13 += hB.y * w1.w;
                a00 += hA.z * w2.x; a01 += hA.z * w2.y; a02 += hA.z * w2.z; a03 += hA.z * w2.w;
                a10 += hB.z * w2.x; a11 += hB.z * w2.y; a12 += hB.z * w2.z; a13 += hB.z * w2.w;
                a00 += hA.w * w3.x; a01 += hA.w * w3.y; a02 += hA.w * w3.z; a03 += hA.w * w3.w;
                a10 += hB.w * w3.x; a11 += hB.w * w3.y; a12 += hB.w * w3.z; a13 += hB.w * w3.w;
            }
            float4 o;
            o.x = a00; o.y = a01; o.z = a02; o.w = a03;
            *(float4*)&pgC[(ksC * 2 + 0) * 392 + j0C] = o;
            o.x = a10; o.y = a11; o.z = a12; o.w = a13;
            *(float4*)&pgC[(ksC * 2 + 1) * 392 + j0C] = o;
        }
        __syncthreads();

        // ===== phase D: h1 update (256 thr) =====
        if (tid < 256) {
            int m = tid >> 7, i = tid & 127;
            float gir = sbih1[i], giz = sbih1[i + 128], gin = sbih1[i + 256];
#pragma unroll
            for (int ks = 0; ks < 8; ks++) {
                int pb = (ks * 2 + m) * 392;
                gir += pgC[pb + i];
                giz += pgC[pb + i + 128];
                gin += pgC[pb + i + 256];
            }
            float ghr = sbhh1[i], ghz = sbhh1[i + 128], ghn = sbhh1[i + 256];
#pragma unroll
            for (int ks = 0; ks < 4; ks++) {
                int pb = (ks * 2 + m) * 392;
                ghr += pgB[pb + i];
                ghz += pgB[pb + i + 128];
                ghn += pgB[pb + i + 256];
            }
            float rr = 1.0f / (1.0f + expf(-(gir + ghr)));
            float zz = 1.0f / (1.0f + expf(-(giz + ghz)));
            float nn = tanhf(gin + rr * ghn);
            h1s[m * 132 + i] = (1.0f - zz) * nn + zz * h1s[m * 132 + i];
        }
        __syncthreads();

        // ===== phase E: logits partials (200 thr) =====
        if (tid < 200) {
            int ks = tid / 100, n = tid - ks * 100;
            int kk0p = ks * 64;
            const float* Zp = &Zs[n * 132 + kk0p];
            const float* hp = &h1s[kk0p];
            float a0 = 0.f, a1 = 0.f;
#pragma unroll 4
            for (int q = 0; q < 16; q++) {
                float4 z4 = *(const float4*)(Zp + 4 * q);
                float4 hA = *(const float4*)(hp + 4 * q);
                float4 hB = *(const float4*)(hp + 132 + 4 * q);
                a0 += hA.x * z4.x; a0 += hA.y * z4.y; a0 += hA.z * z4.z; a0 += hA.w * z4.w;
                a1 += hB.x * z4.x; a1 += hB.y * z4.y; a1 += hB.z * z4.z; a1 += hB.w * z4.w;
            }
            pl[(0 * 2 + ks) * 100 + n] = a0;
            pl[(1 * 2 + ks) * 100 + n] = a1;
        }
        __syncthreads();

        // ===== phase F: softmax stats + selection (wave0: sample, wave1: greedy) =====
        if (tid < 128) {
            const int m = tid >> 6, lane = tid & 63;
            float v0, v1 = -__builtin_inff();
            v0 = (pl[(m * 2 + 0) * 100 + lane] + pl[(m * 2 + 1) * 100 + lane]) * SCALEF;
            if (lane + 64 < NN)
                v1 = (pl[(m * 2 + 0) * 100 + lane + 64] + pl[(m * 2 + 1) * 100 + lane + 64]) * SCALEF;
            float mx = fmaxf(v0, v1);
            for (int off = 32; off > 0; off >>= 1) mx = fmaxf(mx, __shfl_xor(mx, off));
            float e = expf(v0 - mx) + ((lane + 64 < NN) ? expf(v1 - mx) : 0.0f);
            for (int off = 32; off > 0; off >>= 1) e += __shfl_xor(e, off);
            float a0 = v0, a1 = v1;
            if (m == 0) {
                a0 += gum[lane];
                if (lane + 64 < NN) a1 += gum[lane + 64];
            }
            float bv; int bi;
            if (a1 > a0) { bv = a1; bi = lane + 64; } else { bv = a0; bi = lane; }
            for (int off = 32; off > 0; off >>= 1) {
                float ov = __shfl_xor(bv, off);
                int   oi = __shfl_xor(bi, off);
                if (ov > bv || (ov == bv && oi < bi)) { bv = ov; bi = oi; }
            }
            int ind = bi;
            float la = __shfl(v0, ind & 63);
            float lb = __shfl(v1, ind & 63);
            float lv = (ind < 64) ? la : lb;
            if (lane == 0) {
                if (m == 0) out[O0 + b * (NN - 1) + t] = lv - mx - logf(e);
                else        out[O4 + (size_t)b * NN * NN + lastm * NN + ind] = 1.0f;
                s_ind2[m] = ind;
            }
            dist += dis[b * NN * NN + lastm * NN + ind];
            lastm = ind;
        }
        __syncthreads();
    }

    if (tid == 0)  out[O1 + b] = dist;
    if (tid == 64) out[O2 + b] = dist;
}

// ---------------- host launcher ----------------
extern "C" void kernel_launch(void* const* d_in, const int* in_sizes, int n_in,
                              void* d_out, int out_size, void* d_ws, size_t ws_size,
                              hipStream_t stream) {
    (void)in_sizes; (void)n_in; (void)out_size; (void)ws_size;
    const float* node   = (const float*)d_in[0];
    const float* demand = (const float*)d_in[1];
    const float* dis    = (const float*)d_in[2];
    const float* Wn0    = (const float*)d_in[3];
    const float* bn0    = (const float*)d_in[4];
    const float* Ws     = (const float*)d_in[5];
    const float* Wngh   = (const float*)d_in[6];
    const float* We     = (const float*)d_in[7];
    const float* be     = (const float*)d_in[8];
    const float* Wih    = (const float*)d_in[9];
    const float* Whh    = (const float*)d_in[10];
    const float* bih    = (const float*)d_in[11];
    const float* bhh    = (const float*)d_in[12];
    const float* Wq     = (const float*)d_in[13];
    const float* Wc     = (const float*)d_in[14];
    const float* bc     = (const float*)d_in[15];
    float* out = (float*)d_out;
    float* ws  = (float*)d_ws;

    float* hA  = ws;                // 819200
    float* hB  = ws + 819200;       // 819200
    float* hw  = ws + 1638400;      // hw during encoder; Z after
    float* A   = ws + 2457600;      // A during encoder
    float* P0  = ws + 2457600;      // P0 overlays A after encoder
    float* WqT = ws + 4915200;      // 16384

    // fused: embed + adj + Wq transpose + predict + zero (all independent parts)
    hipLaunchKernelGGL(k_pre0, dim3(6739), dim3(256), 0, stream,
                       node, demand, Wn0, bn0, dis, We, be, Wc, bc, Wq,
                       hA, A, WqT, out + O3, out + O4);

    float* cur = hA;
    float* nxt = hB;
    for (int l = 0; l < 3; l++) {
        hipLaunchKernelGGL(k_hw16, dim3(400), dim3(256), 0, stream, cur, Wngh + l * 16384, hw);
        hipLaunchKernelGGL(k_agg10, dim3(640), dim3(256), 0, stream, cur, Ws + l * 16384, A, hw, nxt);
        float* tswap = cur; cur = nxt; nxt = tswap;
    }
    // cur == hB holds the final encoder output

    hipLaunchKernelGGL(k_zp, dim3(400, 4), dim3(256), 0, stream, cur, WqT, Wih, bih, hw, P0);

    hipLaunchKernelGGL(k_decode10, dim3(64), dim3(768), 0, stream,
                       P0, hw, dis, Wih, Whh, bih, bhh, out);
}

// Round 12
// 909.063 us; speedup vs baseline: 2.2784x; 1.0021x over previous
//
#include <hip/hip_runtime.h>
#include <math.h>

// Problem constants
#define BB 64
#define NN 100
#define HH 128
#define T3 384

// Output layout (floats, concatenated in return order)
#define O0 0            // sample_logprob [64,99]
#define O1 6336         // sample_distance [64,1]
#define O2 6400         // greedy_distance [64,1]
#define O3 6464         // predict_matrix [64,100,100,2]
#define O4 1286464      // greedy_solution_matrix [64,100,100]

#define TINYF 1.17549435e-38f
#define SCALEF 0.08838834764831845f

// ---------------- threefry2x32 (exact JAX implementation) ----------------
__device__ __forceinline__ unsigned rotl32(unsigned x, int d) {
    return (x << d) | (x >> (32 - d));
}

__device__ __forceinline__ void tf2x32(unsigned ks0, unsigned ks1,
                                       unsigned x0, unsigned x1,
                                       unsigned& o0, unsigned& o1) {
    unsigned ks2 = ks0 ^ ks1 ^ 0x1BD11BDAu;
    x0 += ks0; x1 += ks1;
    x0 += x1; x1 = rotl32(x1, 13); x1 ^= x0;
    x0 += x1; x1 = rotl32(x1, 15); x1 ^= x0;
    x0 += x1; x1 = rotl32(x1, 26); x1 ^= x0;
    x0 += x1; x1 = rotl32(x1, 6);  x1 ^= x0;
    x0 += ks1; x1 += ks2 + 1u;
    x0 += x1; x1 = rotl32(x1, 17); x1 ^= x0;
    x0 += x1; x1 = rotl32(x1, 29); x1 ^= x0;
    x0 += x1; x1 = rotl32(x1, 16); x1 ^= x0;
    x0 += x1; x1 = rotl32(x1, 24); x1 ^= x0;
    x0 += ks2; x1 += ks0 + 2u;
    x0 += x1; x1 = rotl32(x1, 13); x1 ^= x0;
    x0 += x1; x1 = rotl32(x1, 15); x1 ^= x0;
    x0 += x1; x1 = rotl32(x1, 26); x1 ^= x0;
    x0 += x1; x1 = rotl32(x1, 6);  x1 ^= x0;
    x0 += ks0; x1 += ks1 + 3u;
    x0 += x1; x1 = rotl32(x1, 17); x1 ^= x0;
    x0 += x1; x1 = rotl32(x1, 29); x1 ^= x0;
    x0 += x1; x1 = rotl32(x1, 16); x1 ^= x0;
    x0 += x1; x1 = rotl32(x1, 24); x1 ^= x0;
    x0 += ks1; x1 += ks2 + 4u;
    x0 += x1; x1 = rotl32(x1, 13); x1 ^= x0;
    x0 += x1; x1 = rotl32(x1, 15); x1 ^= x0;
    x0 += x1; x1 = rotl32(x1, 26); x1 ^= x0;
    x0 += x1; x1 = rotl32(x1, 6);  x1 ^= x0;
    x0 += ks2; x1 += ks0 + 5u;
    o0 = x0; o1 = x1;
}

__device__ __forceinline__ float gumbel_f(unsigned k0, unsigned k1, unsigned f) {
    unsigned o0, o1;
    tf2x32(k0, k1, 0u, f, o0, o1);
    unsigned bits = o0 ^ o1;
    float u01 = __uint_as_float((bits >> 9) | 0x3F800000u) - 1.0f;
    float u = fmaxf(TINYF, u01 * (1.0f - TINYF) + TINYF);
    return -logf(-logf(u));
}

// ---------------- fused pre-kernel: embed + adj + transpose + predict + zero ----------
__global__ void k_pre0(const float* __restrict__ node, const float* __restrict__ demand,
                       const float* __restrict__ Wn0, const float* __restrict__ bn0,
                       const float* __restrict__ dis,
                       const float* __restrict__ We, const float* __restrict__ be,
                       const float* __restrict__ Wc, const float* __restrict__ bc,
                       const float* __restrict__ Wq,
                       float* __restrict__ h, float* __restrict__ A,
                       float* __restrict__ WqT,
                       float* __restrict__ out3, float* __restrict__ zp) {
    __shared__ float sWe[128], sbe[128], sc0[128], sc1[128];
    int bid = blockIdx.x, tid = threadIdx.x;
    if (bid < 3200) {
        int idx = bid * 256 + tid;
        int r = idx >> 7, c = idx & 127;
        float v = node[r * 2] * Wn0[c] + node[r * 2 + 1] * Wn0[128 + c]
                + demand[r] * Wn0[256 + c] + bn0[c];
        h[idx] = fmaxf(v, 0.0f);
    } else if (bid < 4800) {
        int row = (bid - 3200) * 4 + (tid >> 6);
        int l = tid & 63;
        const float* d = dis + row * NN;
        float v0 = -d[l];
        float v1 = (l + 64 < NN) ? -d[l + 64] : -__builtin_inff();
        float m = fmaxf(v0, v1);
        for (int off = 32; off > 0; off >>= 1) m = fmaxf(m, __shfl_xor(m, off));
        float e0 = expf(v0 - m);
        float e1 = (l + 64 < NN) ? expf(v1 - m) : 0.0f;
        float s = e0 + e1;
        for (int off = 32; off > 0; off >>= 1) s += __shfl_xor(s, off);
        float inv = 1.0f / s;
        A[row * NN + l] = e0 * inv;
        if (l + 64 < NN) A[row * NN + l + 64] = e1 * inv;
    } else if (bid < 4864) {
        int i = (bid - 4800) * 256 + tid;
        int k = i >> 7, c = i & 127;
        WqT[k * 128 + c] = Wq[c * 128 + k];
    } else if (bid < 6114) {
        if (tid < 128) {
            sWe[tid] = We[tid];
            sbe[tid] = be[tid];
            sc0[tid] = Wc[tid * 2];
            sc1[tid] = Wc[tid * 2 + 1];
        }
        __syncthreads();
        float b0 = bc[0], b1 = bc[1];
        int p0 = (bid - 4864) * 512 + tid, p1 = p0 + 256;
        float d0 = dis[p0], d1 = dis[p1];
        float a00 = b0, a01 = b1, a10 = b0, a11 = b1;
        for (int k4 = 0; k4 < 32; k4++) {
            float4 we = *(const float4*)&sWe[4 * k4];
            float4 bb = *(const float4*)&sbe[4 * k4];
            float4 c0 = *(const float4*)&sc0[4 * k4];
            float4 c1 = *(const float4*)&sc1[4 * k4];
            float e0, e1;
            e0 = fmaxf(d0 * we.x + bb.x, 0.0f); a00 += e0 * c0.x; a01 += e0 * c1.x;
            e1 = fmaxf(d1 * we.x + bb.x, 0.0f); a10 += e1 * c0.x; a11 += e1 * c1.x;
            e0 = fmaxf(d0 * we.y + bb.y, 0.0f); a00 += e0 * c0.y; a01 += e0 * c1.y;
            e1 = fmaxf(d1 * we.y + bb.y, 0.0f); a10 += e1 * c0.y; a11 += e1 * c1.y;
            e0 = fmaxf(d0 * we.z + bb.z, 0.0f); a00 += e0 * c0.z; a01 += e0 * c1.z;
            e1 = fmaxf(d1 * we.z + bb.z, 0.0f); a10 += e1 * c0.z; a11 += e1 * c1.z;
            e0 = fmaxf(d0 * we.w + bb.w, 0.0f); a00 += e0 * c0.w; a01 += e0 * c1.w;
            e1 = fmaxf(d1 * we.w + bb.w, 0.0f); a10 += e1 * c0.w; a11 += e1 * c1.w;
        }
        {
            float m = fmaxf(a00, a01);
            float q0 = expf(a00 - m), q1 = expf(a01 - m);
            float inv = 1.0f / (q0 + q1);
            out3[p0 * 2] = q0 * inv;
            out3[p0 * 2 + 1] = q1 * inv;
        }
        {
            float m = fmaxf(a10, a11);
            float q0 = expf(a10 - m), q1 = expf(a11 - m);
            float inv = 1.0f / (q0 + q1);
            out3[p1 * 2] = q0 * inv;
            out3[p1 * 2 + 1] = q1 * inv;
        }
    } else {
        int i = (bid - 6114) * 256 + tid;
        float4 z; z.x = 0.f; z.y = 0.f; z.z = 0.f; z.w = 0.f;
        ((float4*)zp)[i] = z;
    }
}

// out[6400x128] = h @ W[128x128]; 16 rows/block; float4 h reads, ordered FMAs
__global__ void k_hw16(const float* __restrict__ h, const float* __restrict__ W,
                       float* __restrict__ out) {
    __shared__ float hs[16 * 128];
    int block_row = blockIdx.x * 16;
    int tid = threadIdx.x;
    int col = tid & 127;
    int rg = tid >> 7;
    for (int i = tid; i < 16 * 32; i += 256)
        ((float4*)hs)[i] = ((const float4*)(h + block_row * 128))[i];
    __syncthreads();
    float acc[8] = {0.f, 0.f, 0.f, 0.f, 0.f, 0.f, 0.f, 0.f};
    for (int k4 = 0; k4 < 32; k4++) {
        int k = 4 * k4;
        float w0 = W[k * 128 + col], w1 = W[(k + 1) * 128 + col];
        float w2 = W[(k + 2) * 128 + col], w3 = W[(k + 3) * 128 + col];
#pragma unroll
        for (int r = 0; r < 8; r++) {
            float4 h4 = *(const float4*)&hs[(rg + 2 * r) * 128 + k];
            acc[r] += h4.x * w0; acc[r] += h4.y * w1;
            acc[r] += h4.z * w2; acc[r] += h4.w * w3;
        }
    }
#pragma unroll
    for (int r = 0; r < 8; r++)
        out[(block_row + rg + 2 * r) * 128 + col] = acc[r];
}

// fused Z (h@WqT) + P0 (h@Wih0+bih0); grid (400, 4); float4 h reads
__global__ void k_zp(const float* __restrict__ h, const float* __restrict__ WqT,
                     const float* __restrict__ Wih, const float* __restrict__ bih,
                     float* __restrict__ Z, float* __restrict__ P0) {
    __shared__ float hs[16 * 128];
    int block_row = blockIdx.x * 16;
    int tid = threadIdx.x;
    int c = tid & 127;
    int rg = tid >> 7;
    int y = blockIdx.y;
    for (int i = tid; i < 16 * 32; i += 256)
        ((float4*)hs)[i] = ((const float4*)(h + block_row * 128))[i];
    __syncthreads();
    float acc[8] = {0.f, 0.f, 0.f, 0.f, 0.f, 0.f, 0.f, 0.f};
    if (y == 0) {
        for (int k4 = 0; k4 < 32; k4++) {
            int k = 4 * k4;
            float w0 = WqT[k * 128 + c], w1 = WqT[(k + 1) * 128 + c];
            float w2 = WqT[(k + 2) * 128 + c], w3 = WqT[(k + 3) * 128 + c];
#pragma unroll
            for (int r = 0; r < 8; r++) {
                float4 h4 = *(const float4*)&hs[(rg + 2 * r) * 128 + k];
                acc[r] += h4.x * w0; acc[r] += h4.y * w1;
                acc[r] += h4.z * w2; acc[r] += h4.w * w3;
            }
        }
#pragma unroll
        for (int r = 0; r < 8; r++)
            Z[(block_row + rg + 2 * r) * 128 + c] = acc[r];
    } else {
        int col = (y - 1) * 128 + c;
        for (int k4 = 0; k4 < 32; k4++) {
            int k = 4 * k4;
            float w0 = Wih[k * 384 + col], w1 = Wih[(k + 1) * 384 + col];
            float w2 = Wih[(k + 2) * 384 + col], w3 = Wih[(k + 3) * 384 + col];
#pragma unroll
            for (int r = 0; r < 8; r++) {
                float4 h4 = *(const float4*)&hs[(rg + 2 * r) * 128 + k];
                acc[r] += h4.x * w0; acc[r] += h4.y * w1;
                acc[r] += h4.z * w2; acc[r] += h4.w * w3;
            }
        }
        float bb = bih[col];
#pragma unroll
        for (int r = 0; r < 8; r++)
            P0[(size_t)(block_row + rg + 2 * r) * 384 + col] = acc[r] + bb;
    }
}

// h' = relu(h@Ws + A@hw); 10 rows/block; float4 hs/As reads, ordered FMAs
__global__ void k_agg10(const float* __restrict__ h, const float* __restrict__ Ws,
                        const float* __restrict__ A, const float* __restrict__ hw,
                        float* __restrict__ out) {
    __shared__ float hs[10 * 128];
    __shared__ float As[10 * 100];
    int b = blockIdx.x / 10;
    int i0 = (blockIdx.x % 10) * 10;
    int tid = threadIdx.x;
    int col = tid & 127;
    int rg = tid >> 7;
    int rowbase = b * NN + i0;
    for (int i = tid; i < 10 * 32; i += 256)
        ((float4*)hs)[i] = ((const float4*)(h + rowbase * 128))[i];
    for (int i = tid; i < 10 * 25; i += 256)
        ((float4*)As)[i] = ((const float4*)(A + rowbase * 100))[i];
    __syncthreads();
    float acc[5] = {0.f, 0.f, 0.f, 0.f, 0.f};
    for (int k4 = 0; k4 < 32; k4++) {
        int k = 4 * k4;
        float w0 = Ws[k * 128 + col], w1 = Ws[(k + 1) * 128 + col];
        float w2 = Ws[(k + 2) * 128 + col], w3 = Ws[(k + 3) * 128 + col];
#pragma unroll
        for (int r = 0; r < 5; r++) {
            float4 h4 = *(const float4*)&hs[(rg + 2 * r) * 128 + k];
            acc[r] += h4.x * w0; acc[r] += h4.y * w1;
            acc[r] += h4.z * w2; acc[r] += h4.w * w3;
        }
    }
    const float* hwb = hw + b * NN * 128;
    for (int j4 = 0; j4 < 25; j4++) {
        int j = 4 * j4;
        float v0 = hwb[j * 128 + col], v1 = hwb[(j + 1) * 128 + col];
        float v2 = hwb[(j + 2) * 128 + col], v3 = hwb[(j + 3) * 128 + col];
#pragma unroll
        for (int r = 0; r < 5; r++) {
            float4 a4 = *(const float4*)&As[(rg + 2 * r) * 100 + j];
            acc[r] += a4.x * v0; acc[r] += a4.y * v1;
            acc[r] += a4.z * v2; acc[r] += a4.w * v3;
        }
    }
#pragma unroll
    for (int r = 0; r < 5; r++)
        out[(rowbase + rg + 2 * r) * 128 + col] = fmaxf(acc[r], 0.0f);
}

// ---------------- shared matvec tile (spill-proof, ~40 VGPR) ----------------
__device__ __forceinline__ void matvec_tile4(const float* __restrict__ W,   // &W[k0*384 + j0]
                                             const float* __restrict__ hp,  // &h[k0]; modes +0,+132
                                             int nk4,
                                             float* __restrict__ pg0,
                                             float* __restrict__ pg1) {
    float a00 = 0.f, a01 = 0.f, a02 = 0.f, a03 = 0.f;
    float a10 = 0.f, a11 = 0.f, a12 = 0.f, a13 = 0.f;
#pragma unroll 4
    for (int k4 = 0; k4 < nk4; ++k4) {
        float4 hA = *(const float4*)(hp + 4 * k4);
        float4 hB = *(const float4*)(hp + 132 + 4 * k4);
        const float* Wk = W + (size_t)(4 * k4) * T3;
        float4 w0 = *(const float4*)(Wk);
        float4 w1 = *(const float4*)(Wk + T3);
        float4 w2 = *(const float4*)(Wk + 2 * T3);
        float4 w3 = *(const float4*)(Wk + 3 * T3);
        a00 += hA.x * w0.x; a01 += hA.x * w0.y; a02 += hA.x * w0.z; a03 += hA.x * w0.w;
        a10 += hB.x * w0.x; a11 += hB.x * w0.y; a12 += hB.x * w0.z; a13 += hB.x * w0.w;
        a00 += hA.y * w1.x; a01 += hA.y * w1.y; a02 += hA.y * w1.z; a03 += hA.y * w1.w;
        a10 += hB.y * w1.x; a11 += hB.y * w1.y; a12 += hB.y * w1.z; a13 += hB.y * w1.w;
        a00 += hA.z * w2.x; a01 += hA.z * w2.y; a02 += hA.z * w2.z; a03 += hA.z * w2.w;
        a10 += hB.z * w2.x; a11 += hB.z * w2.y; a12 += hB.z * w2.z; a13 += hB.z * w2.w;
        a00 += hA.w * w3.x; a01 += hA.w * w3.y; a02 += hA.w * w3.z; a03 += hA.w * w3.w;
        a10 += hB.w * w3.x; a11 += hB.w * w3.y; a12 += hB.w * w3.z; a13 += hB.w * w3.w;
    }
    float4 o;
    o.x = a00; o.y = a01; o.z = a02; o.w = a03;
    *(float4*)pg0 = o;
    o.x = a10; o.y = a11; o.z = a12; o.w = a13;
    *(float4*)pg1 = o;
}

// ---------------- decoder v11: decode10 + asm-PINNED Wih1 register tile ----------------
// decode10's loop-invariant pw[16] tile was silently rematerialized by the allocator
// (VGPR stayed 84, time unchanged). The empty asm with "+v" constraints makes the
// loaded values opaque — they cannot be re-derived from memory, forcing true
// register residency. Sentinels: VGPR ~148 (pin engaged), WRITE ~37 KB (no spill).
__global__ __launch_bounds__(768, 3) void k_decode11(
    const float* __restrict__ P0,       // [6400, 384]  x@Wih0 + bih0
    const float* __restrict__ Z,        // [6400, 128]  x@Wq^T
    const float* __restrict__ dis,
    const float* __restrict__ Wih,      // [2,128,384]
    const float* __restrict__ Whh,      // [2,128,384]
    const float* __restrict__ bih,
    const float* __restrict__ bhh,
    float* __restrict__ out) {
    __shared__ float Zs[NN * 132];          // 52.8 KB
    __shared__ float h0s[2 * 132], h1s[2 * 132];
    __shared__ float pgA[4 * 2 * 392];      // gh0 partials [ks4][m][392]
    __shared__ float pgB[4 * 2 * 392];      // gh1 partials
    __shared__ float pgC[8 * 2 * 392];      // gi1 partials [ks8][m][392]
    __shared__ float sbhh0[T3], sbih1[T3], sbhh1[T3];
    __shared__ float pl[2 * 2 * 100];       // [m][ks][n]
    __shared__ float gum[128];
    __shared__ int s_ind2[2];

    const int tid = threadIdx.x;
    const int b = blockIdx.x;

    const float* __restrict__ Wih1 = Wih + 128 * T3;

    // phase-A matvec role (all 768 threads)
    const int unitA = tid / 384;             // 0: Whh0*h0 -> pgA, 1: Whh1*h1 -> pgB
    const int rA = tid - unitA * 384;
    const int ksA = rA / 96, j4A = rA - ksA * 96;
    const int j0A = j4A * 4, k0A = ksA * 32;
    // phase-C matvec role
    const int ksC = tid / 96, j4C = tid - ksC * 96;
    const int j0C = j4C * 4, k0C = ksC * 16;

    // ---- load step-invariant Wih1 tile (16 float4 = 64 VGPR) and PIN it ----
    float4 pw[16];
    {
        const float* Wc = Wih1 + (size_t)k0C * T3 + j0C;
#pragma unroll
        for (int k = 0; k < 16; k++)
            pw[k] = *(const float4*)(Wc + (size_t)k * T3);
    }
#pragma unroll
    for (int k = 0; k < 16; k++) {
        asm volatile("" : "+v"(pw[k].x), "+v"(pw[k].y), "+v"(pw[k].z), "+v"(pw[k].w));
    }

    // ---- static staging ----
    for (int i4 = tid; i4 < NN * 32; i4 += 768) {
        int r = i4 >> 5, c4 = (i4 & 31) * 4;
        *(float4*)&Zs[r * 132 + c4] = *(const float4*)&Z[(b * NN + r) * 128 + c4];
    }
    if (tid < T3) {
        sbhh0[tid] = bhh[tid];
        sbih1[tid] = bih[T3 + tid];
        sbhh1[tid] = bhh[T3 + tid];
    }
    if (tid < 256) {
        int m = tid >> 7, i = tid & 127;
        h0s[m * 132 + i] = 0.0f;
        h1s[m * 132 + i] = 0.0f;
    }
    if (tid == 0) { s_ind2[0] = 0; s_ind2[1] = 0; }

    unsigned kk0, kk1;
    tf2x32(0u, 42u, 0u, 0u, kk0, kk1);   // k1 of split(key(42)); advanced uniformly below

    int lastm = 0;       // tracked by tid<128 (selection threads)
    float dist = 0.0f;
    __syncthreads();

    for (int t = 0; t < NN - 1; t++) {
        // ---- RNG chain advance (uniform in all threads) ----
        unsigned sk0, sk1, nkA, nkB;
        tf2x32(kk0, kk1, 0u, 1u, sk0, sk1);
        tf2x32(kk0, kk1, 0u, 0u, nkA, nkB);
        kk0 = nkA; kk1 = nkB;

        // ---- gi0 prefetch into registers (loads in flight during phase A) ----
        float pf_r = 0.f, pf_z = 0.f, pf_n = 0.f;
        if (tid < 256) {
            const float* P0row = P0 + (size_t)(b * NN + s_ind2[tid >> 7]) * T3;
            int i = tid & 127;
            pf_r = P0row[i];
            pf_z = P0row[i + 128];
            pf_n = P0row[i + 256];
        }

        // ===== phase A: gh0 & gh1 partials — all 768 threads stream Whh =====
        {
            const float* W = Whh + unitA * (128 * T3) + (size_t)k0A * T3 + j0A;
            const float* hp = ((unitA == 0) ? h0s : h1s) + k0A;
            float* pg = (unitA == 0) ? pgA : pgB;
            matvec_tile4(W, hp, 8,
                         &pg[(ksA * 2 + 0) * 392 + j0A],
                         &pg[(ksA * 2 + 1) * 392 + j0A]);
        }
        __syncthreads();

        // ===== phase B: h0 update (256 thr) + gumbel (thr 256..355) =====
        if (tid < 256) {
            int m = tid >> 7, i = tid & 127;
            float ghr = sbhh0[i], ghz = sbhh0[i + 128], ghn = sbhh0[i + 256];
#pragma unroll
            for (int ks = 0; ks < 4; ks++) {
                int pb = (ks * 2 + m) * 392;
                ghr += pgA[pb + i];
                ghz += pgA[pb + i + 128];
                ghn += pgA[pb + i + 256];
            }
            float rr = 1.0f / (1.0f + expf(-(pf_r + ghr)));
            float zz = 1.0f / (1.0f + expf(-(pf_z + ghz)));
            float nn = tanhf(pf_n + rr * ghn);
            h0s[m * 132 + i] = (1.0f - zz) * nn + zz * h0s[m * 132 + i];
        } else if (tid < 356) {
            int u = tid - 256;
            gum[u] = gumbel_f(sk0, sk1, (unsigned)(b * NN + u));
        }
        __syncthreads();

        // ===== phase C: gi1 partials — weights from PINNED registers, zero loads =====
        {
            const float* hp = h0s + k0C;
            float a00 = 0.f, a01 = 0.f, a02 = 0.f, a03 = 0.f;
            float a10 = 0.f, a11 = 0.f, a12 = 0.f, a13 = 0.f;
#pragma unroll
            for (int k4 = 0; k4 < 4; ++k4) {
                float4 hA = *(const float4*)(hp + 4 * k4);
                float4 hB = *(const float4*)(hp + 132 + 4 * k4);
                float4 w0 = pw[4 * k4 + 0];
                float4 w1 = pw[4 * k4 + 1];
                float4 w2 = pw[4 * k4 + 2];
                float4 w3 = pw[4 * k4 + 3];
                a00 += hA.x * w0.x; a01 += hA.x * w0.y; a02 += hA.x * w0.z; a03 += hA.x * w0.w;
                a10 += hB.x * w0.x; a11 += hB.x * w0.y; a12 += hB.x * w0.z; a13 += hB.x * w0.w;
                a00 += hA.y * w1.x; a01 += hA.y * w1.y; a02 += hA.y * w1.z; a03 += hA.y * w1.w;
                a10 += hB.y * w1.x; a11 += hB.y * w1.y; a12 += hB.y * w1.z; a13 += hB.y * w1.w;
                a00 += hA.z * w2.x; a01 += hA.z * w2.y; a02 += hA.z * w2.z; a03 += hA.z * w2.w;
                a10 += hB.z * w2.x; a11 += hB.z * w2.y; a12 += hB.z * w2.z; a13 += hB.z * w2.w;
                a00 += hA.w * w3.x; a01 += hA.w * w3.y; a02 += hA.w * w3.z; a03 += hA.w * w3.w;
                a10 += hB.w * w3.x; a11 += hB.w * w3.y; a12 += hB.w * w3.z; a13 += hB.w * w3.w;
            }
            float4 o;
            o.x = a00; o.y = a01; o.z = a02; o.w = a03;
            *(float4*)&pgC[(ksC * 2 + 0) * 392 + j0C] = o;
            o.x = a10; o.y = a11; o.z = a12; o.w = a13;
            *(float4*)&pgC[(ksC * 2 + 1) * 392 + j0C] = o;
        }
        __syncthreads();

        // ===== phase D: h1 update (256 thr) =====
        if (tid < 256) {
            int m = tid >> 7, i = tid & 127;
            float gir = sbih1[i], giz = sbih1[i + 128], gin = sbih1[i + 256];
#pragma unroll
            for (int ks = 0; ks < 8; ks++) {
                int pb = (ks * 2 + m) * 392;
                gir += pgC[pb + i];
                giz += pgC[pb + i + 128];
                gin += pgC[pb + i + 256];
            }
            float ghr = sbhh1[i], ghz = sbhh1[i + 128], ghn = sbhh1[i + 256];
#pragma unroll
            for (int ks = 0; ks < 4; ks++) {
                int pb = (ks * 2 + m) * 392;
                ghr += pgB[pb + i];
                ghz += pgB[pb + i + 128];
                ghn += pgB[pb + i + 256];
            }
            float rr = 1.0f / (1.0f + expf(-(gir + ghr)));
            float zz = 1.0f / (1.0f + expf(-(giz + ghz)));
            float nn = tanhf(gin + rr * ghn);
            h1s[m * 132 + i] = (1.0f - zz) * nn + zz * h1s[m * 132 + i];
        }
        __syncthreads();

        // ===== phase E: logits partials (200 thr) =====
        if (tid < 200) {
            int ks = tid / 100, n = tid - ks * 100;
            int kk0p = ks * 64;
            const float* Zp = &Zs[n * 132 + kk0p];
            const float* hp = &h1s[kk0p];
            float a0 = 0.f, a1 = 0.f;
#pragma unroll 4
            for (int q = 0; q < 16; q++) {
                float4 z4 = *(const float4*)(Zp + 4 * q);
                float4 hA = *(const float4*)(hp + 4 * q);
                float4 hB = *(const float4*)(hp + 132 + 4 * q);
                a0 += hA.x * z4.x; a0 += hA.y * z4.y; a0 += hA.z * z4.z; a0 += hA.w * z4.w;
                a1 += hB.x * z4.x; a1 += hB.y * z4.y; a1 += hB.z * z4.z; a1 += hB.w * z4.w;
            }
            pl[(0 * 2 + ks) * 100 + n] = a0;
            pl[(1 * 2 + ks) * 100 + n] = a1;
        }
        __syncthreads();

        // ===== phase F: softmax stats + selection (wave0: sample, wave1: greedy) =====
        if (tid < 128) {
            const int m = tid >> 6, lane = tid & 63;
            float v0, v1 = -__builtin_inff();
            v0 = (pl[(m * 2 + 0) * 100 + lane] + pl[(m * 2 + 1) * 100 + lane]) * SCALEF;
            if (lane + 64 < NN)
                v1 = (pl[(m * 2 + 0) * 100 + lane + 64] + pl[(m * 2 + 1) * 100 + lane + 64]) * SCALEF;
            float mx = fmaxf(v0, v1);
            for (int off = 32; off > 0; off >>= 1) mx = fmaxf(mx, __shfl_xor(mx, off));
            float e = expf(v0 - mx) + ((lane + 64 < NN) ? expf(v1 - mx) : 0.0f);
            for (int off = 32; off > 0; off >>= 1) e += __shfl_xor(e, off);
            float a0 = v0, a1 = v1;
            if (m == 0) {
                a0 += gum[lane];
                if (lane + 64 < NN) a1 += gum[lane + 64];
            }
            float bv; int bi;
            if (a1 > a0) { bv = a1; bi = lane + 64; } else { bv = a0; bi = lane; }
            for (int off = 32; off > 0; off >>= 1) {
                float ov = __shfl_xor(bv, off);
                int   oi = __shfl_xor(bi, off);
                if (ov > bv || (ov == bv && oi < bi)) { bv = ov; bi = oi; }
            }
            int ind = bi;
            float la = __shfl(v0, ind & 63);
            float lb = __shfl(v1, ind & 63);
            float lv = (ind < 64) ? la : lb;
            if (lane == 0) {
                if (m == 0) out[O0 + b * (NN - 1) + t] = lv - mx - logf(e);
                else        out[O4 + (size_t)b * NN * NN + lastm * NN + ind] = 1.0f;
                s_ind2[m] = ind;
            }
            dist += dis[b * NN * NN + lastm * NN + ind];
            lastm = ind;
        }
        __syncthreads();
    }

    if (tid == 0)  out[O1 + b] = dist;
    if (tid == 64) out[O2 + b] = dist;
}

// ---------------- host launcher ----------------
extern "C" void kernel_launch(void* const* d_in, const int* in_sizes, int n_in,
                              void* d_out, int out_size, void* d_ws, size_t ws_size,
                              hipStream_t stream) {
    (void)in_sizes; (void)n_in; (void)out_size; (void)ws_size;
    const float* node   = (const float*)d_in[0];
    const float* demand = (const float*)d_in[1];
    const float* dis    = (const float*)d_in[2];
    const float* Wn0    = (const float*)d_in[3];
    const float* bn0    = (const float*)d_in[4];
    const float* Ws     = (const float*)d_in[5];
    const float* Wngh   = (const float*)d_in[6];
    const float* We     = (const float*)d_in[7];
    const float* be     = (const float*)d_in[8];
    const float* Wih    = (const float*)d_in[9];
    const float* Whh    = (const float*)d_in[10];
    const float* bih    = (const float*)d_in[11];
    const float* bhh    = (const float*)d_in[12];
    const float* Wq     = (const float*)d_in[13];
    const float* Wc     = (const float*)d_in[14];
    const float* bc     = (const float*)d_in[15];
    float* out = (float*)d_out;
    float* ws  = (float*)d_ws;

    float* hA  = ws;                // 819200
    float* hB  = ws + 819200;       // 819200
    float* hw  = ws + 1638400;      // hw during encoder; Z after
    float* A   = ws + 2457600;      // A during encoder
    float* P0  = ws + 2457600;      // P0 overlays A after encoder
    float* WqT = ws + 4915200;      // 16384

    // fused: embed + adj + Wq transpose + predict + zero (all independent parts)
    hipLaunchKernelGGL(k_pre0, dim3(6739), dim3(256), 0, stream,
                       node, demand, Wn0, bn0, dis, We, be, Wc, bc, Wq,
                       hA, A, WqT, out + O3, out + O4);

    float* cur = hA;
    float* nxt = hB;
    for (int l = 0; l < 3; l++) {
        hipLaunchKernelGGL(k_hw16, dim3(400), dim3(256), 0, stream, cur, Wngh + l * 16384, hw);
        hipLaunchKernelGGL(k_agg10, dim3(640), dim3(256), 0, stream, cur, Ws + l * 16384, A, hw, nxt);
        float* tswap = cur; cur = nxt; nxt = tswap;
    }
    // cur == hB holds the final encoder output

    hipLaunchKernelGGL(k_zp, dim3(400, 4), dim3(256), 0, stream, cur, WqT, Wih, bih, hw, P0);

    hipLaunchKernelGGL(k_decode11, dim3(64), dim3(768), 0, stream,
                       P0, hw, dis, Wih, Whh, bih, bhh, out);
}